// Round 7
// baseline (2035.991 us; speedup 1.0000x reference)
//
#include <hip/hip_runtime.h>
#include <hip/hip_bf16.h>
#include <cstdint>
#include <cstddef>

// ---------------------------------------------------------------------------
// MMPrompt pipeline, round 7:
//  - mgemm2: 128x256 tile (32 MFMA / barrier pair) + bijective XCD swizzle
//    for the final GEMM and the two RGCN h-GEMMs.
//  - graph gather chains in bf16 (k_gcn_gb): halved random-read traffic,
//    fused accumulate (no f32 intermediates, no copies).
//  - everything else as round 6 (proven: 0 bank conflicts, no races).
// ---------------------------------------------------------------------------

namespace {

constexpr int NE   = 30000;
constexpr int NM   = 6000;
constexpr int Dm   = 384;
constexpr int Hm   = 768;
constexpr int EKG  = 200000;
constexpr int EC   = 200000;
constexpr int ES   = 80000;
constexpr int Bc   = 16;
constexpr int LE   = 48;
constexpr int NTOK = 4096;
constexpr int NO   = 18432;

constexpr size_t NBf = (size_t)NE * Dm;   // 11,520,000
constexpr size_t MBF = (size_t)NM * Dm;   // 2,304,000

// ---------------- d_out arena (f32-unit offsets) ----------------
// phase A (conversions + RGCN)
constexpr size_t P_XB    = 0;          // xb bf16 NE*384           ends 5,760,000
constexpr size_t P_WCT   = 5760000;    // wcat_t bf16 12*384*384   ends 6,644,736
constexpr size_t P_CNT   = 6644736;    // rcp cnt f32 12*NE        ends 7,004,736
constexpr size_t P_ENT0  = 7004736;    // f32 NE*384               ends 18,524,736
constexpr size_t P_HH    = 18524736;   // h bf16 NE*2304           ends 53,084,736
constexpr size_t P_DIS   = 53084736;   // disc+dist+disi f32 42,000 ends 53,126,736
// phase B (graph chains) — xb/wct/rcpc dead after RGCN; ent0 dead after cvt
constexpr size_t P_E0B   = 0;          // ent0b bf16 NE*384  ends 2,880,000
constexpr size_t P_C1B   = 2880000;    // bf16 NE*384        ends 5,760,000
constexpr size_t P_C2B   = 5760000;    // bf16 NE*384        ends 8,640,000
constexpr size_t P_NFB   = 8640000;    // bf16 NM*384        ends 9,792,000
constexpr size_t P_T1B   = 9800000;    // bf16 NM*384        ends 10,952,000
constexpr size_t P_G1    = 11000000;   // f32 NM*384         ends 13,304,000
constexpr size_t P_ACC   = 41564736;   // f32 NE*384 (over dead hh) ends 53,084,736
constexpr size_t P_ENTB  = 55600000;   // bf16 NE*384        ends 61,360,000
// phase C (MLP/token/attn) — all phase-B small buffers dead
constexpr size_t P_HIDB  = 0;          // bf16 NE*192   ends 2,880,000
constexpr size_t P_ENT2B = 2880000;    // bf16 NE*384   ends 8,640,000
constexpr size_t P_E768B = 8640000;    // bf16 NE*768   ends 20,160,000
constexpr size_t P_TOKB  = 20160000;   // bf16 4096*768 ends 21,732,864
constexpr size_t P_THIDB = 21732864;   // bf16 4096*384 ends 22,519,296
constexpr size_t P_TOK1B = 22519296;   // bf16 4096*768
constexpr size_t P_TOK2B = 24092160;   // bf16 4096*768
constexpr size_t P_QB    = 25665024;   // bf16 4096*768
constexpr size_t P_EEMB  = 27237888;   // bf16 768*Hm    ends 27,532,800
constexpr size_t P_PR0   = 27532800;   // f32 4096*768   ends 30,678,528
constexpr size_t P_PR0B  = 30678528;   // bf16 4096*768  ends 32,251,392
constexpr size_t P_PHIDB = 32251392;   // bf16 4096*384  ends 33,037,824
// whole-launch small weights (never read by the final GEMM)
constexpr size_t P_WT    = 74000000;   // ends 75,474,560 < 75,497,472
constexpr size_t S_ROOT  = 0;
constexpr size_t S_EP1A  = 147456;
constexpr size_t S_EP1B  = 221184;
constexpr size_t S_EP2   = 294912;
constexpr size_t S_TP1A  = 589824;
constexpr size_t S_TP1B  = 884736;
constexpr size_t S_TP2   = 1179648;
constexpr size_t S_CAW   = 1769472;
constexpr size_t S_PP1A  = 2359296;
constexpr size_t S_PP1B  = 2654208;

// ---------------- d_ws layout (bytes) ----------------
constexpr size_t WI       = 6291456 / 4;
constexpr size_t I_CNT    = WI + 0;
constexpr size_t I_PART   = WI + 30000;
constexpr size_t I_KG_RP  = WI + 30256;
constexpr size_t I_KG_CUR = WI + 60256;
constexpr size_t I_KG_SL  = WI + 90256;
constexpr size_t I_C_RP   = WI + 290256;
constexpr size_t I_C_CUR  = WI + 320256;
constexpr size_t I_C_SL   = WI + 350256;
constexpr size_t I_TS_RP  = WI + 550256;
constexpr size_t I_TS_CUR = WI + 556256;
constexpr size_t I_TS_SL  = WI + 562256;
constexpr size_t I_IS_RP  = WI + 642256;
constexpr size_t I_IS_CUR = WI + 648256;
constexpr size_t I_IS_SL  = WI + 654256;       // ends byte 9,228,480
constexpr size_t WS_PP2T_BYTE = 6291456;
constexpr size_t WS_NEED      = 34603008;

inline int cdiv(long a, long b) { return (int)((a + b - 1) / b); }

} // namespace

typedef short short8v __attribute__((ext_vector_type(8)));
typedef float f32x4 __attribute__((ext_vector_type(4)));

__device__ __forceinline__ unsigned short f2bf(float f) {
  union { float f; uint32_t u; } v; v.f = f;
  uint32_t u = v.u;
  u += 0x7fffu + ((u >> 16) & 1u);
  return (unsigned short)(u >> 16);
}
__device__ __forceinline__ uint32_t pkbf(float a, float b) {
  __hip_bfloat162 h = __float22bfloat162_rn(float2{a, b});
  union { __hip_bfloat162 h; uint32_t u; } cv; cv.h = h;
  return cv.u;
}
__device__ __forceinline__ float bflo(uint32_t u) {
  union { uint32_t u; float f; } c; c.u = u << 16; return c.f;
}
__device__ __forceinline__ float bfhi(uint32_t u) {
  union { uint32_t u; float f; } c; c.u = u & 0xFFFF0000u; return c.f;
}

__device__ __forceinline__ void gl16(const void* g, void* l) {
  __builtin_amdgcn_global_load_lds(
      (const __attribute__((address_space(1))) void*)g,
      (__attribute__((address_space(3))) void*)l, 16, 0, 0);
}

// ---------------------------------------------------------------------------
// conversion / utility kernels
// ---------------------------------------------------------------------------

__global__ void k_cvt(const float* __restrict__ x, unsigned short* __restrict__ o, size_t n2) {
  size_t i = (size_t)blockIdx.x * 256 + threadIdx.x;
  if (i >= n2) return;
  float2 v = *(const float2*)(x + 2 * i);
  *(uint32_t*)(o + 2 * i) = pkbf(v.x, v.y);
}

// f32 W[K][N] -> bf16 Wt[N][K]
__global__ void k_cvt_t(const float* __restrict__ W, unsigned short* __restrict__ Wt,
                        int K, int N) {
  __shared__ float t[32][33];
  int tx = threadIdx.x & 31, ty = threadIdx.x >> 5;
  int n0 = blockIdx.x * 32, k0 = blockIdx.y * 32;
#pragma unroll
  for (int j = 0; j < 4; ++j)
    t[ty + 8 * j][tx] = W[(size_t)(k0 + ty + 8 * j) * N + n0 + tx];
  __syncthreads();
#pragma unroll
  for (int j = 0; j < 4; ++j) {
    int n = ty + 8 * j;
    Wt[(size_t)(n0 + n) * K + k0 + tx] = f2bf(t[tx][n]);
  }
}

// wcat_t[(r*384+o)*384 + i] = sum_b comp[r][b]*bases[b][i][o]  (bf16)
__global__ void k_wcat(const float* __restrict__ comp, const float* __restrict__ bases,
                       unsigned short* __restrict__ Wt) {
  int idx = blockIdx.x * 256 + threadIdx.x;
  if (idx >= 12 * Dm * Dm) return;
  int i = idx % Dm;
  int o = (idx / Dm) % Dm;
  int r = idx / (Dm * Dm);
  float s = 0.f;
#pragma unroll
  for (int b = 0; b < 8; ++b)
    s += comp[r * 8 + b] * bases[(size_t)b * Dm * Dm + (size_t)i * Dm + o];
  Wt[idx] = f2bf(s);
}

__global__ void k_scale_ip(float* __restrict__ d, float a, size_t n) {
  size_t i = (size_t)blockIdx.x * 256 + threadIdx.x;
  if (i < n) d[i] *= a;
}

// gather bf16 rows as u32 chunks
__global__ void k_gather_b(const int* __restrict__ idx, const uint32_t* __restrict__ x2,
                           uint32_t* __restrict__ out2, int rows, int D2) {
  size_t i = (size_t)blockIdx.x * 256 + threadIdx.x;
  if (i >= (size_t)rows * D2) return;
  int r = (int)(i / D2);
  int c = (int)(i - (size_t)r * D2);
  out2[i] = x2[(size_t)idx[r] * D2 + c];
}

// ent[mte[m]][d] += 0.25*g[m][d]
__global__ void k_scatter_movie(const int* __restrict__ mte, const float* __restrict__ g,
                                float* __restrict__ ent) {
  size_t i = (size_t)blockIdx.x * 256 + threadIdx.x;
  if (i >= MBF) return;
  int m = (int)(i / Dm);
  int d = (int)(i - (size_t)m * Dm);
  atomicAdd(&ent[(size_t)mte[m] * Dm + d], 0.25f * g[i]);
}

// ---------------------------------------------------------------------------
// CSR build
// ---------------------------------------------------------------------------

__global__ void k_hist(const int* __restrict__ dst, int* __restrict__ cnt, int E) {
  int e = blockIdx.x * 256 + threadIdx.x;
  if (e < E) atomicAdd(&cnt[dst[e]], 1);
}

__global__ void k_scan_blk(const int* __restrict__ in, int* __restrict__ out,
                           int* __restrict__ part, int n) {
  __shared__ int s[256];
  int t = threadIdx.x;
  int g = blockIdx.x * 256 + t;
  int v = (g < n) ? in[g] : 0;
  s[t] = v;
  __syncthreads();
  for (int off = 1; off < 256; off <<= 1) {
    int add = (t >= off) ? s[t - off] : 0;
    __syncthreads();
    s[t] += add;
    __syncthreads();
  }
  if (g < n) out[g] = s[t] - v;
  if (t == 255) part[blockIdx.x] = s[255];
}

__global__ void k_scan_top(int* __restrict__ part, int nb) {
  __shared__ int s[256];
  int t = threadIdx.x;
  int v = (t < nb) ? part[t] : 0;
  s[t] = v;
  __syncthreads();
  for (int off = 1; off < 256; off <<= 1) {
    int add = (t >= off) ? s[t - off] : 0;
    __syncthreads();
    s[t] += add;
    __syncthreads();
  }
  if (t < nb) part[t] = s[t] - v;
}

__global__ void k_scan_add(int* __restrict__ out, const int* __restrict__ part, int n) {
  int g = blockIdx.x * 256 + threadIdx.x;
  if (g < n) out[g] += part[blockIdx.x];
}

__global__ void k_fill(const int* __restrict__ src, const int* __restrict__ dst,
                       const int* __restrict__ typ, int* __restrict__ cur,
                       int* __restrict__ slots, int E) {
  int e = blockIdx.x * 256 + threadIdx.x;
  if (e >= E) return;
  int d = dst[e];
  int pos = atomicAdd(&cur[d], 1);
  int v = src[e];
  if (typ) v |= (typ[e] << 16);
  slots[pos] = v;
}

__global__ void k_dis_rp(const int* __restrict__ rp, float* __restrict__ dis, int n, int E) {
  int v = blockIdx.x * 256 + threadIdx.x;
  if (v >= n) return;
  int e0 = rp[v], e1 = (v + 1 < n) ? rp[v + 1] : E;
  dis[v] = rsqrtf((float)(e1 - e0) + 1.0f);
}

__global__ void k_count_type(const int* __restrict__ dst, const int* __restrict__ typ,
                             float* __restrict__ cnt, int E) {
  int i = blockIdx.x * 256 + threadIdx.x;
  if (i < E) atomicAdd(&cnt[(size_t)typ[i] * NE + dst[i]], 1.0f);
}

__global__ void k_rcp(float* __restrict__ c, size_t n) {
  size_t i = (size_t)blockIdx.x * 256 + threadIdx.x;
  if (i < n) { float v = c[i]; c[i] = (v > 0.f) ? 1.0f / v : 0.f; }
}

// ---------------------------------------------------------------------------
// bf16 gather kernel: one wave per dst row. x bf16 [n][384].
// out = dv*(dv*x[v] + sum dis[s]*x[s])  (bf16, if OUTW)
// ACCM: 1 -> acc += val; 2 -> acc = x[v] + val; 3 -> acc = val
// ---------------------------------------------------------------------------
template <bool OUTW, int ACCM>
__global__ void k_gcn_gb(const unsigned short* __restrict__ x,
                         const float* __restrict__ dis,
                         const int* __restrict__ rp, const int* __restrict__ slots,
                         unsigned short* __restrict__ outb, float* __restrict__ acc,
                         int n, int E) {
  int v = (int)((blockIdx.x * (size_t)blockDim.x + threadIdx.x) >> 6);
  int lane = threadIdx.x & 63;
  if (v >= n) return;
  float dv = dis[v];
  const uint32_t* xr = (const uint32_t*)(x + (size_t)v * Dm);
  float xv[6];
#pragma unroll
  for (int i = 0; i < 3; ++i) {
    uint32_t u = xr[lane + 64 * i];
    xv[2 * i] = bflo(u); xv[2 * i + 1] = bfhi(u);
  }
  float a[6];
#pragma unroll
  for (int i = 0; i < 6; ++i) a[i] = dv * xv[i];
  int e0 = rp[v], e1 = (v + 1 < n) ? rp[v + 1] : E;
  for (int e = e0; e < e1; ++e) {
    int s = slots[e];
    float c = dis[s];
    const uint32_t* xs = (const uint32_t*)(x + (size_t)s * Dm);
#pragma unroll
    for (int i = 0; i < 3; ++i) {
      uint32_t u = xs[lane + 64 * i];
      a[2 * i]     = fmaf(c, bflo(u), a[2 * i]);
      a[2 * i + 1] = fmaf(c, bfhi(u), a[2 * i + 1]);
    }
  }
#pragma unroll
  for (int i = 0; i < 6; ++i) a[i] *= dv;
  if (OUTW) {
    uint32_t* ob = (uint32_t*)(outb + (size_t)v * Dm);
#pragma unroll
    for (int i = 0; i < 3; ++i) ob[lane + 64 * i] = pkbf(a[2 * i], a[2 * i + 1]);
  }
  float* ar = acc + (size_t)v * Dm;
#pragma unroll
  for (int i = 0; i < 3; ++i) {
    int cidx = 2 * (lane + 64 * i);
    float2 w;
    if (ACCM == 1) {
      float2 old = *(const float2*)(ar + cidx);
      w = float2{old.x + a[2 * i], old.y + a[2 * i + 1]};
    } else if (ACCM == 2) {
      w = float2{xv[2 * i] + a[2 * i], xv[2 * i + 1] + a[2 * i + 1]};
    } else {
      w = float2{a[2 * i], a[2 * i + 1]};
    }
    *(float2*)(ar + cidx) = w;
  }
}

// ent0[v] += sum_{e: rbase<=r<rbase+6} rcp[r][v] * hh[src][(r-rbase)*384 + c]
__global__ void k_rgcn_g(const unsigned short* __restrict__ hh, const float* __restrict__ rcp,
                         const int* __restrict__ rp, const int* __restrict__ slots,
                         float* __restrict__ ent0, int rbase, int E) {
  int v = (int)((blockIdx.x * (size_t)blockDim.x + threadIdx.x) >> 6);
  int lane = threadIdx.x & 63;
  if (v >= NE) return;
  int e0 = rp[v], e1 = (v + 1 < NE) ? rp[v + 1] : E;
  float* er = ent0 + (size_t)v * Dm;
  float2 a[3];
#pragma unroll
  for (int i = 0; i < 3; ++i) a[i] = *(const float2*)(er + 2 * lane + 128 * i);
  for (int e = e0; e < e1; ++e) {
    int p = slots[e];
    int r = p >> 16, s = p & 0xFFFF;
    if (r < rbase || r >= rbase + 6) continue;
    float nm = rcp[(size_t)r * NE + v];
    const unsigned short* hr = hh + (size_t)s * 2304 + (size_t)(r - rbase) * 384;
#pragma unroll
    for (int i = 0; i < 3; ++i) {
      uint32_t u = *(const uint32_t*)(hr + 2 * lane + 128 * i);
      a[i].x = fmaf(nm, bflo(u), a[i].x);
      a[i].y = fmaf(nm, bfhi(u), a[i].y);
    }
  }
#pragma unroll
  for (int i = 0; i < 3; ++i) *(float2*)(er + 2 * lane + 128 * i) = a[i];
}

// ---------------------------------------------------------------------------
// bf16 MFMA GEMM, 128x128 (m97 structure). A[M][K], Wt[N][K] bf16.
// OUT: 0 = f32 C, 1 = bf16 C.
// ---------------------------------------------------------------------------
template <bool RELU, bool RES, int OUT>
__global__ __launch_bounds__(256) void mgemm_bf(
    const unsigned short* __restrict__ A, const unsigned short* __restrict__ Wt,
    const float* __restrict__ bias, const float* __restrict__ Rp,
    void* __restrict__ Cv, int M, int N, int K) {
  __shared__ __align__(16) unsigned short As[128 * 64];
  __shared__ __align__(16) unsigned short Bs[128 * 64];
  const int tid = threadIdx.x;
  const int lane = tid & 63;
  const int w = tid >> 6;
  const int bm = blockIdx.x * 128, bn = blockIdx.y * 128;
  const int wr = (w >> 1) * 64, wc = (w & 1) * 64;
  const int lrow = lane & 15, lq = lane >> 4;
  f32x4 acc[4][4] = {};
  const int prow_l = lane >> 3;
  const int pslot = lane & 7;

  for (int k0 = 0; k0 < K; k0 += 64) {
    __syncthreads();
#pragma unroll
    for (int j = 0; j < 4; ++j) {
      int seg = j * 4 + w;
      int prow = seg * 8 + prow_l;
      int aslot = pslot ^ (prow & 7);
      int arow = min(bm + prow, M - 1);
      gl16(A + (size_t)arow * K + k0 + aslot * 8, &As[seg * 512 + lane * 8]);
    }
#pragma unroll
    for (int j = 0; j < 4; ++j) {
      int seg = j * 4 + w;
      int prow = seg * 8 + prow_l;
      int bslot = pslot ^ (prow & 7);
      int brow = min(bn + prow, N - 1);
      gl16(Wt + (size_t)brow * K + k0 + bslot * 8, &Bs[seg * 512 + lane * 8]);
    }
    __syncthreads();
#pragma unroll
    for (int ks = 0; ks < 2; ++ks) {
      short8v af[4], bf[4];
      const int slot = ks * 4 + lq;
#pragma unroll
      for (int mr = 0; mr < 4; ++mr) {
        int r = wr + mr * 16 + lrow;
        af[mr] = *(const short8v*)&As[r * 64 + ((slot ^ (r & 7)) << 3)];
      }
#pragma unroll
      for (int nc = 0; nc < 4; ++nc) {
        int r = wc + nc * 16 + lrow;
        bf[nc] = *(const short8v*)&Bs[r * 64 + ((slot ^ (r & 7)) << 3)];
      }
#pragma unroll
      for (int mr = 0; mr < 4; ++mr)
#pragma unroll
        for (int nc = 0; nc < 4; ++nc)
          acc[mr][nc] = __builtin_amdgcn_mfma_f32_16x16x32_bf16(
              af[mr], bf[nc], acc[mr][nc], 0, 0, 0);
    }
  }
#pragma unroll
  for (int mr = 0; mr < 4; ++mr) {
#pragma unroll
    for (int e = 0; e < 4; ++e) {
      int r = bm + wr + mr * 16 + lq * 4 + e;
      if (r >= M) continue;
#pragma unroll
      for (int nc = 0; nc < 4; ++nc) {
        int c = bn + wc + nc * 16 + lrow;
        if (c >= N) continue;
        float v = acc[mr][nc][e];
        if (bias) v += bias[c];
        if (RES) v += Rp[(size_t)r * N + c];
        if (RELU) v = fmaxf(v, 0.f);
        if (OUT == 0) ((float*)Cv)[(size_t)r * N + c] = v;
        else ((unsigned short*)Cv)[(size_t)r * N + c] = f2bf(v);
      }
    }
  }
}

// ---------------------------------------------------------------------------
// bf16 MFMA GEMM, 128x256 tile (32 MFMA per barrier pair), bijective XCD
// swizzle. OUT: 1 = bf16 C, 2 = f32 transposed prompt layout. N%256==0.
// ---------------------------------------------------------------------------
template <int OUT>
__global__ __launch_bounds__(256) void mgemm2(
    const unsigned short* __restrict__ A, const unsigned short* __restrict__ Wt,
    const float* __restrict__ bias, void* __restrict__ Cv, int M, int N, int K) {
  __shared__ __align__(16) unsigned short As[128 * 64];
  __shared__ __align__(16) unsigned short Bs[256 * 64];
  const int tid = threadIdx.x;
  const int lane = tid & 63;
  const int w = tid >> 6;
  // bijective XCD swizzle (m204)
  const int nwg = gridDim.x * gridDim.y;
  const int bid = blockIdx.y * gridDim.x + blockIdx.x;
  const int q = nwg >> 3, r8 = nwg & 7, xcd = bid & 7, off = bid >> 3;
  const int swz = (xcd < r8 ? xcd * (q + 1) : r8 * (q + 1) + (xcd - r8) * q) + off;
  const int bm = (swz % gridDim.x) * 128;
  const int bn = (swz / gridDim.x) * 256;
  const int wr = (w >> 1) * 64, wc = (w & 1) * 128;
  const int lrow = lane & 15, lq = lane >> 4;
  f32x4 acc[4][8] = {};
  const int prow_l = lane >> 3;
  const int pslot = lane & 7;

  for (int k0 = 0; k0 < K; k0 += 64) {
    __syncthreads();
#pragma unroll
    for (int j = 0; j < 4; ++j) {
      int seg = j * 4 + w;
      int prow = seg * 8 + prow_l;
      int aslot = pslot ^ (prow & 7);
      int arow = min(bm + prow, M - 1);
      gl16(A + (size_t)arow * K + k0 + aslot * 8, &As[seg * 512 + lane * 8]);
    }
#pragma unroll
    for (int j = 0; j < 8; ++j) {
      int seg = j * 4 + w;
      int prow = seg * 8 + prow_l;
      int bslot = pslot ^ (prow & 7);
      gl16(Wt + (size_t)(bn + prow) * K + k0 + bslot * 8, &Bs[seg * 512 + lane * 8]);
    }
    __syncthreads();
#pragma unroll
    for (int ks = 0; ks < 2; ++ks) {
      short8v af[4], bf[8];
      const int slot = ks * 4 + lq;
#pragma unroll
      for (int mr = 0; mr < 4; ++mr) {
        int rr = wr + mr * 16 + lrow;
        af[mr] = *(const short8v*)&As[rr * 64 + ((slot ^ (rr & 7)) << 3)];
      }
#pragma unroll
      for (int nc = 0; nc < 8; ++nc) {
        int rr = wc + nc * 16 + lrow;
        bf[nc] = *(const short8v*)&Bs[rr * 64 + ((slot ^ (rr & 7)) << 3)];
      }
#pragma unroll
      for (int mr = 0; mr < 4; ++mr)
#pragma unroll
        for (int nc = 0; nc < 8; ++nc)
          acc[mr][nc] = __builtin_amdgcn_mfma_f32_16x16x32_bf16(
              af[mr], bf[nc], acc[mr][nc], 0, 0, 0);
    }
  }
#pragma unroll
  for (int mr = 0; mr < 4; ++mr) {
#pragma unroll
    for (int e = 0; e < 4; ++e) {
      int r = bm + wr + mr * 16 + lq * 4 + e;
      if (r >= M) continue;
#pragma unroll
      for (int nc = 0; nc < 8; ++nc) {
        int c = bn + wc + nc * 16 + lrow;
        float v = acc[mr][nc][e];
        if (bias) v += bias[c];
        if (OUT == 1) {
          ((unsigned short*)Cv)[(size_t)r * N + c] = f2bf(v);
        } else {
          int b = r >> 8, t = r & 255;
          int l = c / 1536, rem = c - l * 1536;
          int blk = rem / 768, rem2 = rem - blk * 768;
          int hh = rem2 >> 6, dd = rem2 & 63;
          size_t oi = (((((size_t)l * 2 + blk) * 16 + b) * 12 + hh) * 256 + t) * 64 + dd;
          ((float*)Cv)[oi] = v;
        }
      }
    }
  }
}

// Fallback FINAL GEMM (ws too small): W f32 from d_in, in-kernel conversion.
__global__ __launch_bounds__(256) void mgemm_fin(
    const unsigned short* __restrict__ A, const float* __restrict__ W,
    const float* __restrict__ bias, float* __restrict__ O, int M, int N, int K) {
  __shared__ __align__(16) unsigned short As[128 * 64];
  __shared__ __align__(16) unsigned short Bs[128 * 64];
  const int tid = threadIdx.x;
  const int lane = tid & 63;
  const int w = tid >> 6;
  const int bm = blockIdx.x * 128, bn = blockIdx.y * 128;
  const int wr = (w >> 1) * 64, wc = (w & 1) * 64;
  const int lrow = lane & 15, lq = lane >> 4;
  f32x4 acc[4][4] = {};
  const int prow_l = lane >> 3;
  const int pslot = lane & 7;
  const int n_loc = tid & 127;
  const int kh = (tid >> 7) * 32;

  for (int k0 = 0; k0 < K; k0 += 64) {
    __syncthreads();
#pragma unroll
    for (int j = 0; j < 4; ++j) {
      int seg = j * 4 + w;
      int prow = seg * 8 + prow_l;
      int aslot = pslot ^ (prow & 7);
      gl16(A + (size_t)(bm + prow) * K + k0 + aslot * 8, &As[seg * 512 + lane * 8]);
    }
    float wv[32];
    const float* wp = W + (size_t)(k0 + kh) * N + bn + n_loc;
#pragma unroll
    for (int j = 0; j < 32; ++j) wv[j] = wp[(size_t)j * N];
#pragma unroll
    for (int c = 0; c < 4; ++c) {
      uint32_t u0 = pkbf(wv[8 * c + 0], wv[8 * c + 1]);
      uint32_t u1 = pkbf(wv[8 * c + 2], wv[8 * c + 3]);
      uint32_t u2 = pkbf(wv[8 * c + 4], wv[8 * c + 5]);
      uint32_t u3 = pkbf(wv[8 * c + 6], wv[8 * c + 7]);
      int s = (kh >> 3) + c;
      *(uint4*)&Bs[n_loc * 64 + ((s ^ (n_loc & 7)) << 3)] = uint4{u0, u1, u2, u3};
    }
    __syncthreads();
#pragma unroll
    for (int ks = 0; ks < 2; ++ks) {
      short8v af[4], bf[4];
      const int slot = ks * 4 + lq;
#pragma unroll
      for (int mr = 0; mr < 4; ++mr) {
        int r = wr + mr * 16 + lrow;
        af[mr] = *(const short8v*)&As[r * 64 + ((slot ^ (r & 7)) << 3)];
      }
#pragma unroll
      for (int nc = 0; nc < 4; ++nc) {
        int r = wc + nc * 16 + lrow;
        bf[nc] = *(const short8v*)&Bs[r * 64 + ((slot ^ (r & 7)) << 3)];
      }
#pragma unroll
      for (int mr = 0; mr < 4; ++mr)
#pragma unroll
        for (int nc = 0; nc < 4; ++nc)
          acc[mr][nc] = __builtin_amdgcn_mfma_f32_16x16x32_bf16(
              af[mr], bf[nc], acc[mr][nc], 0, 0, 0);
    }
  }
#pragma unroll
  for (int mr = 0; mr < 4; ++mr) {
#pragma unroll
    for (int e = 0; e < 4; ++e) {
      int r = bm + wr + mr * 16 + lq * 4 + e;
      int b = r >> 8, t = r & 255;
#pragma unroll
      for (int nc = 0; nc < 4; ++nc) {
        int c = bn + wc + nc * 16 + lrow;
        float v = acc[mr][nc][e] + bias[c];
        int l = c / 1536, rem = c - l * 1536;
        int blk = rem / 768, rem2 = rem - blk * 768;
        int hh = rem2 >> 6, dd = rem2 & 63;
        size_t oi = (((((size_t)l * 2 + blk) * 16 + b) * 12 + hh) * 256 + t) * 64 + dd;
        O[oi] = v;
      }
    }
  }
}

// ---------------------------------------------------------------------------
// fused cross-attention (bf16 inputs): one wave per (b,t)
// ---------------------------------------------------------------------------
__global__ __launch_bounds__(256) void k_attn(
    const unsigned short* __restrict__ qb, const unsigned short* __restrict__ eb_all,
    const unsigned short* __restrict__ tokb, float* __restrict__ pr0,
    unsigned short* __restrict__ pr0b) {
  int gw = (int)((blockIdx.x * (size_t)blockDim.x + threadIdx.x) >> 6);
  int lane = threadIdx.x & 63;
  if (gw >= NTOK) return;
  int b = gw >> 8;
  const unsigned short* qr = qb + (size_t)gw * Hm;
  float2 q[6];
#pragma unroll
  for (int i = 0; i < 6; ++i) {
    uint32_t u = *(const uint32_t*)(qr + 2 * lane + 128 * i);
    q[i] = float2{bflo(u), bfhi(u)};
  }
  const unsigned short* eb = eb_all + (size_t)b * LE * Hm;
  float myA = -3.0e38f;
  for (int e = 0; e < LE; ++e) {
    const unsigned short* er = eb + (size_t)e * Hm;
    float s = 0.f;
#pragma unroll
    for (int i = 0; i < 6; ++i) {
      uint32_t u = *(const uint32_t*)(er + 2 * lane + 128 * i);
      s = fmaf(q[i].x, bflo(u), s);
      s = fmaf(q[i].y, bfhi(u), s);
    }
#pragma unroll
    for (int off = 32; off > 0; off >>= 1) s += __shfl_xor(s, off);
    if (lane == e) myA = s * (1.0f / 768.0f);
  }
  float mx = myA;
#pragma unroll
  for (int off = 32; off > 0; off >>= 1) mx = fmaxf(mx, __shfl_xor(mx, off));
  float p = (lane < LE) ? expf(myA - mx) : 0.f;
  float sum = p;
#pragma unroll
  for (int off = 32; off > 0; off >>= 1) sum += __shfl_xor(sum, off);
  float wgt = p / sum;
  const unsigned short* tr = tokb + (size_t)gw * Hm;
  float2 a[6];
#pragma unroll
  for (int i = 0; i < 6; ++i) {
    uint32_t u = *(const uint32_t*)(tr + 2 * lane + 128 * i);
    a[i] = float2{bflo(u), bfhi(u)};
  }
  for (int e = 0; e < LE; ++e) {
    float we = __shfl(wgt, e);
    const unsigned short* er = eb + (size_t)e * Hm;
#pragma unroll
    for (int i = 0; i < 6; ++i) {
      uint32_t u = *(const uint32_t*)(er + 2 * lane + 128 * i);
      a[i].x = fmaf(we, bflo(u), a[i].x);
      a[i].y = fmaf(we, bfhi(u), a[i].y);
    }
  }
  float* orow = pr0 + (size_t)gw * Hm;
  unsigned short* obrow = pr0b + (size_t)gw * Hm;
#pragma unroll
  for (int i = 0; i < 6; ++i) {
    *(float2*)(orow + 2 * lane + 128 * i) = a[i];
    *(uint32_t*)(obrow + 2 * lane + 128 * i) = pkbf(a[i].x, a[i].y);
  }
}

// ---------------------------------------------------------------------------

extern "C" void kernel_launch(void* const* d_in, const int* in_sizes, int n_in,
                              void* d_out, int out_size, void* d_ws, size_t ws_size,
                              hipStream_t stream) {
  (void)in_sizes; (void)n_in; (void)out_size;

  const float* x_node = (const float*)d_in[0];
  const float* bases  = (const float*)d_in[1];
  const float* comp   = (const float*)d_in[2];
  const float* root   = (const float*)d_in[3];
  const float* rbias  = (const float*)d_in[4];
  const float* ep1w1  = (const float*)d_in[5];
  const float* ep1b1  = (const float*)d_in[6];
  const float* ep1w2  = (const float*)d_in[7];
  const float* ep1b2  = (const float*)d_in[8];
  const float* ep2w   = (const float*)d_in[9];
  const float* ep2b   = (const float*)d_in[10];
  const float* tp1w1  = (const float*)d_in[11];
  const float* tp1b1  = (const float*)d_in[12];
  const float* tp1w2  = (const float*)d_in[13];
  const float* tp1b2  = (const float*)d_in[14];
  const float* tp2w   = (const float*)d_in[15];
  const float* tp2b   = (const float*)d_in[16];
  const float* caw    = (const float*)d_in[17];
  const float* pp1w1  = (const float*)d_in[18];
  const float* pp1b1  = (const float*)d_in[19];
  const float* pp1w2  = (const float*)d_in[20];
  const float* pp1b2  = (const float*)d_in[21];
  const float* pp2w   = (const float*)d_in[22];
  const float* pp2b   = (const float*)d_in[23];
  const float* tokens = (const float*)d_in[24];
  const int* ei_kg = (const int*)d_in[25];
  const int* etype = (const int*)d_in[26];
  const int* ei_c  = (const int*)d_in[27];
  const int* ei_ts = (const int*)d_in[28];
  const int* ei_is = (const int*)d_in[29];
  const int* mte   = (const int*)d_in[30];
  const int* eids  = (const int*)d_in[31];

  float* O = (float*)d_out;
  unsigned short* xb    = (unsigned short*)(O + P_XB);
  unsigned short* wct   = (unsigned short*)(O + P_WCT);
  float* rcpc  = O + P_CNT;
  float* ent0  = O + P_ENT0;
  unsigned short* hh    = (unsigned short*)(O + P_HH);
  float* disc  = O + P_DIS;
  float* dist  = O + P_DIS + 30000;
  float* disi  = O + P_DIS + 36000;
  unsigned short* ent0b = (unsigned short*)(O + P_E0B);
  unsigned short* c1b   = (unsigned short*)(O + P_C1B);
  unsigned short* c2b   = (unsigned short*)(O + P_C2B);
  unsigned short* nfb   = (unsigned short*)(O + P_NFB);
  unsigned short* t1b   = (unsigned short*)(O + P_T1B);
  float* g1    = O + P_G1;
  float* accb  = O + P_ACC;
  unsigned short* entb  = (unsigned short*)(O + P_ENTB);
  unsigned short* hidb  = (unsigned short*)(O + P_HIDB);
  unsigned short* ent2b = (unsigned short*)(O + P_ENT2B);
  unsigned short* e768b = (unsigned short*)(O + P_E768B);
  unsigned short* tokb  = (unsigned short*)(O + P_TOKB);
  unsigned short* thidb = (unsigned short*)(O + P_THIDB);
  unsigned short* tok1b = (unsigned short*)(O + P_TOK1B);
  unsigned short* tok2b = (unsigned short*)(O + P_TOK2B);
  unsigned short* qb    = (unsigned short*)(O + P_QB);
  unsigned short* eemb  = (unsigned short*)(O + P_EEMB);
  float* pr0   = O + P_PR0;
  unsigned short* pr0b  = (unsigned short*)(O + P_PR0B);
  unsigned short* phidb = (unsigned short*)(O + P_PHIDB);
  unsigned short* wts   = (unsigned short*)(O + P_WT);

  int* iws = (int*)d_ws;
  unsigned short* p2b = (unsigned short*)d_ws;
  unsigned short* pp2t = (unsigned short*)d_ws + WS_PP2T_BYTE / 2;
  const bool ws_ok = (ws_size >= WS_NEED);
  int* cnt_i  = iws + I_CNT;
  int* part   = iws + I_PART;
  int* kg_rp  = iws + I_KG_RP;  int* kg_cur = iws + I_KG_CUR;  int* kg_sl = iws + I_KG_SL;
  int* c_rp   = iws + I_C_RP;   int* c_cur  = iws + I_C_CUR;   int* c_sl  = iws + I_C_SL;
  int* ts_rp  = iws + I_TS_RP;  int* ts_cur = iws + I_TS_CUR;  int* ts_sl = iws + I_TS_SL;
  int* is_rp  = iws + I_IS_RP;  int* is_cur = iws + I_IS_CUR;  int* is_sl = iws + I_IS_SL;

  const int EW = 256;

  // ---------------- phase A: conversions ----------------
  k_cvt<<<cdiv(NBf / 2, EW), EW, 0, stream>>>(x_node, xb, NBf / 2);
  k_wcat<<<cdiv(12 * Dm * Dm, EW), EW, 0, stream>>>(comp, bases, wct);
  k_cvt_t<<<dim3(Dm / 32, Dm / 32), 256, 0, stream>>>(root, wts + S_ROOT, Dm, Dm);
  k_cvt_t<<<dim3(192 / 32, Dm / 32), 256, 0, stream>>>(ep1w1, wts + S_EP1A, Dm, 192);
  k_cvt_t<<<dim3(Dm / 32, 192 / 32), 256, 0, stream>>>(ep1w2, wts + S_EP1B, 192, Dm);
  k_cvt_t<<<dim3(Hm / 32, Dm / 32), 256, 0, stream>>>(ep2w, wts + S_EP2, Dm, Hm);
  k_cvt_t<<<dim3(Dm / 32, Hm / 32), 256, 0, stream>>>(tp1w1, wts + S_TP1A, Hm, Dm);
  k_cvt_t<<<dim3(Hm / 32, Dm / 32), 256, 0, stream>>>(tp1w2, wts + S_TP1B, Dm, Hm);
  k_cvt_t<<<dim3(Hm / 32, Hm / 32), 256, 0, stream>>>(tp2w, wts + S_TP2, Hm, Hm);
  k_cvt_t<<<dim3(Hm / 32, Hm / 32), 256, 0, stream>>>(caw, wts + S_CAW, Hm, Hm);
  k_cvt_t<<<dim3(Dm / 32, Hm / 32), 256, 0, stream>>>(pp1w1, wts + S_PP1A, Hm, Dm);
  k_cvt_t<<<dim3(Hm / 32, Dm / 32), 256, 0, stream>>>(pp1w2, wts + S_PP1B, Dm, Hm);

  // ---------------- CSR builds ----------------
  auto build_csr = [&](const int* ei, const int* typ, int n, int E,
                       int* rp, int* cur, int* sl) {
    hipMemsetAsync(cnt_i, 0, (size_t)n * 4, stream);
    k_hist<<<cdiv(E, EW), EW, 0, stream>>>(ei + E, cnt_i, E);
    int nb = cdiv(n, 256);
    k_scan_blk<<<nb, 256, 0, stream>>>(cnt_i, rp, part, n);
    k_scan_top<<<1, 256, 0, stream>>>(part, nb);
    k_scan_add<<<nb, 256, 0, stream>>>(rp, part, n);
    hipMemcpyAsync(cur, rp, (size_t)n * 4, hipMemcpyDeviceToDevice, stream);
    k_fill<<<cdiv(E, EW), EW, 0, stream>>>(ei, ei + E, typ, cur, sl, E);
  };
  build_csr(ei_kg, etype, NE, EKG, kg_rp, kg_cur, kg_sl);
  build_csr(ei_c, nullptr, NE, EC, c_rp, c_cur, c_sl);
  build_csr(ei_ts, nullptr, NM, ES, ts_rp, ts_cur, ts_sl);
  build_csr(ei_is, nullptr, NM, ES, is_rp, is_cur, is_sl);

  k_dis_rp<<<cdiv(NE, EW), EW, 0, stream>>>(c_rp, disc, NE, EC);
  k_dis_rp<<<cdiv(NM, EW), EW, 0, stream>>>(ts_rp, dist, NM, ES);
  k_dis_rp<<<cdiv(NM, EW), EW, 0, stream>>>(is_rp, disi, NM, ES);

  hipMemsetAsync(rcpc, 0, (size_t)12 * NE * 4, stream);
  k_count_type<<<cdiv(EKG, EW), EW, 0, stream>>>(ei_kg + EKG, etype, rcpc, EKG);
  k_rcp<<<cdiv((long)12 * NE, EW), EW, 0, stream>>>(rcpc, (size_t)12 * NE);

  // ---------------- RGCN ----------------
  mgemm_bf<false, true, 0><<<dim3(cdiv(NE, 128), cdiv(Dm, 128)), 256, 0, stream>>>(
      xb, wts + S_ROOT, rbias, x_node, ent0, NE, Dm, Dm);
  mgemm2<1><<<dim3(cdiv(NE, 128), (6 * Dm) / 256), 256, 0, stream>>>(
      xb, wct, nullptr, hh, NE, 6 * Dm, Dm);
  k_rgcn_g<<<cdiv((long)NE * 64, EW), EW, 0, stream>>>(hh, rcpc, kg_rp, kg_sl, ent0, 0, EKG);
  mgemm2<1><<<dim3(cdiv(NE, 128), (6 * Dm) / 256), 256, 0, stream>>>(
      xb, wct + (size_t)6 * Dm * Dm, nullptr, hh, NE, 6 * Dm, Dm);
  k_rgcn_g<<<cdiv((long)NE * 64, EW), EW, 0, stream>>>(hh, rcpc, kg_rp, kg_sl, ent0, 6, EKG);

  // ---------------- phase B: bf16 conversion of ent0, then graph chains ---
  k_cvt<<<cdiv(NBf / 2, EW), EW, 0, stream>>>(ent0, ent0b, NBf / 2);
  // movie branch: nfb = ent0b[mte]; g1 = ts1+ts2+is1+is2 (f32)
  k_gather_b<<<cdiv((long)NM * 192, EW), EW, 0, stream>>>(
      mte, (const uint32_t*)ent0b, (uint32_t*)nfb, NM, 192);
  k_gcn_gb<true, 3><<<cdiv((long)NM * 64, EW), EW, 0, stream>>>(
      nfb, dist, ts_rp, ts_sl, t1b, g1, NM, ES);
  k_gcn_gb<false, 1><<<cdiv((long)NM * 64, EW), EW, 0, stream>>>(
      t1b, dist, ts_rp, ts_sl, nullptr, g1, NM, ES);
  k_gcn_gb<true, 1><<<cdiv((long)NM * 64, EW), EW, 0, stream>>>(
      nfb, disi, is_rp, is_sl, t1b, g1, NM, ES);
  k_gcn_gb<false, 1><<<cdiv((long)NM * 64, EW), EW, 0, stream>>>(
      t1b, disi, is_rp, is_sl, nullptr, g1, NM, ES);
  // entity chain: accb = ent0 + c1 + c2 + c3
  k_gcn_gb<true, 2><<<cdiv((long)NE * 64, EW), EW, 0, stream>>>(
      ent0b, disc, c_rp, c_sl, c1b, accb, NE, EC);
  k_gcn_gb<true, 1><<<cdiv((long)NE * 64, EW), EW, 0, stream>>>(
      c1b, disc, c_rp, c_sl, c2b, accb, NE, EC);
  k_gcn_gb<false, 1><<<cdiv((long)NE * 64, EW), EW, 0, stream>>>(
      c2b, disc, c_rp, c_sl, nullptr, accb, NE, EC);
  k_scale_ip<<<cdiv(NBf, EW), EW, 0, stream>>>(accb, 0.25f, NBf);
  k_scatter_movie<<<cdiv(MBF, EW), EW, 0, stream>>>(mte, g1, accb);
  k_cvt<<<cdiv(NBf / 2, EW), EW, 0, stream>>>(accb, entb, NBf / 2);

  // pp2t conversion (CSR arrays now dead)
  if (ws_ok) {
    k_cvt_t<<<dim3(NO / 32, Hm / 32), 256, 0, stream>>>(pp2w, pp2t, Hm, NO);
  }

  // ---------------- entity MLP ----------------
  mgemm_bf<true, false, 1><<<dim3(cdiv(NE, 128), cdiv(192, 128)), 256, 0, stream>>>(
      entb, wts + S_EP1A, ep1b1, nullptr, hidb, NE, 192, Dm);
  mgemm_bf<false, true, 1><<<dim3(cdiv(NE, 128), cdiv(Dm, 128)), 256, 0, stream>>>(
      hidb, wts + S_EP1B, ep1b2, accb, ent2b, NE, Dm, 192);
  mgemm_bf<false, false, 1><<<dim3(cdiv(NE, 128), cdiv(Hm, 128)), 256, 0, stream>>>(
      ent2b, wts + S_EP2, ep2b, nullptr, e768b, NE, Hm, Dm);

  // ---------------- token path ----------------
  k_cvt<<<cdiv((long)NTOK * Hm / 2, EW), EW, 0, stream>>>(tokens, tokb, (size_t)NTOK * Hm / 2);
  mgemm_bf<true, false, 1><<<dim3(cdiv(NTOK, 128), cdiv(Dm, 128)), 256, 0, stream>>>(
      tokb, wts + S_TP1A, tp1b1, nullptr, thidb, NTOK, Dm, Hm);
  mgemm_bf<false, true, 1><<<dim3(cdiv(NTOK, 128), cdiv(Hm, 128)), 256, 0, stream>>>(
      thidb, wts + S_TP1B, tp1b2, tokens, tok1b, NTOK, Hm, Dm);
  mgemm_bf<false, false, 1><<<dim3(cdiv(NTOK, 128), cdiv(Hm, 128)), 256, 0, stream>>>(
      tok1b, wts + S_TP2, tp2b, nullptr, tok2b, NTOK, Hm, Hm);
  mgemm_bf<false, false, 1><<<dim3(cdiv(NTOK, 128), cdiv(Hm, 128)), 256, 0, stream>>>(
      tok2b, wts + S_CAW, nullptr, nullptr, qb, NTOK, Hm, Hm);

  k_gather_b<<<cdiv((long)Bc * LE * (Hm / 2), EW), EW, 0, stream>>>(
      eids, (const uint32_t*)e768b, (uint32_t*)eemb, Bc * LE, Hm / 2);
  k_attn<<<cdiv((long)NTOK * 64, 256), 256, 0, stream>>>(qb, eemb, tok2b, pr0, pr0b);

  mgemm_bf<true, false, 1><<<dim3(cdiv(NTOK, 128), cdiv(Dm, 128)), 256, 0, stream>>>(
      pr0b, wts + S_PP1A, pp1b1, nullptr, phidb, NTOK, Dm, Hm);
  mgemm_bf<false, true, 1><<<dim3(cdiv(NTOK, 128), cdiv(Hm, 128)), 256, 0, stream>>>(
      phidb, wts + S_PP1B, pp1b2, pr0, p2b, NTOK, Hm, Dm);

  // ---------------- final GEMM + transpose (reads ONLY d_ws/d_in) ---------
  if (ws_ok) {
    mgemm2<2><<<dim3(NTOK / 128, NO / 256), 256, 0, stream>>>(
        p2b, pp2t, pp2b, O, NTOK, NO, Hm);
  } else {
    mgemm_fin<<<dim3(NTOK / 128, NO / 128), 256, 0, stream>>>(
        p2b, pp2w, pp2b, O, NTOK, NO, Hm);
  }
}

// Round 8
// 1642.265 us; speedup vs baseline: 1.2397x; 1.2397x over previous
//
#include <hip/hip_runtime.h>
#include <hip/hip_bf16.h>
#include <cstdint>
#include <cstddef>

// ---------------------------------------------------------------------------
// MMPrompt pipeline, round 8:
//  - REVERT r7's mgemm2 (128x256+swizzle regressed: occupancy 12%, FETCH +97MB).
//    All GEMMs back to the proven mgemm_bf 128x128 m97 structure.
//  - Keep bf16 gather chains; fuse 0.25 scaling + bf16 emission into them
//    (removes k_scale_ip and two 69-92MB k_cvt passes).
// ---------------------------------------------------------------------------

namespace {

constexpr int NE   = 30000;
constexpr int NM   = 6000;
constexpr int Dm   = 384;
constexpr int Hm   = 768;
constexpr int EKG  = 200000;
constexpr int EC   = 200000;
constexpr int ES   = 80000;
constexpr int Bc   = 16;
constexpr int LE   = 48;
constexpr int NTOK = 4096;
constexpr int NO   = 18432;

constexpr size_t NBf = (size_t)NE * Dm;   // 11,520,000
constexpr size_t MBF = (size_t)NM * Dm;   // 2,304,000

// ---------------- d_out arena (f32-unit offsets) ----------------
// phase A (conversions + RGCN)
constexpr size_t P_XB    = 0;          // xb bf16 NE*384           ends 5,760,000
constexpr size_t P_WCT   = 5760000;    // wcat_t bf16 12*384*384   ends 6,644,736
constexpr size_t P_CNT   = 6644736;    // rcp cnt f32 12*NE        ends 7,004,736
constexpr size_t P_ENT0  = 7004736;    // f32 NE*384               ends 18,524,736
constexpr size_t P_HH    = 18524736;   // h bf16 NE*2304           ends 53,084,736
constexpr size_t P_DIS   = 53084736;   // disc+dist+disi f32 42,000 ends 53,126,736
// phase B (graph chains) — xb dead after hh GEMM#2; ent0 dead after rgcn#2
constexpr size_t P_E0B   = 0;          // ent0b bf16 NE*384  ends 2,880,000
constexpr size_t P_C1B   = 2880000;    // bf16 NE*384        ends 5,760,000
constexpr size_t P_C2B   = 5760000;    // bf16 NE*384        ends 8,640,000
constexpr size_t P_NFB   = 8640000;    // bf16 NM*384        ends 9,792,000
constexpr size_t P_T1B   = 9800000;    // bf16 NM*384        ends 10,952,000
constexpr size_t P_G1    = 11000000;   // f32 NM*384         ends 13,304,000
constexpr size_t P_ACC   = 41564736;   // f32 NE*384 (over dead hh) ends 53,084,736
constexpr size_t P_ENTB  = 55600000;   // bf16 NE*384        ends 61,360,000
// phase C (MLP/token/attn) — all phase-B small buffers dead
constexpr size_t P_HIDB  = 0;          // bf16 NE*192   ends 1,440,000
constexpr size_t P_ENT2B = 2880000;    // bf16 NE*384   ends 8,640,000
constexpr size_t P_E768B = 8640000;    // bf16 NE*768   ends 20,160,000
constexpr size_t P_TOKB  = 20160000;   // bf16 4096*768 ends 21,732,864
constexpr size_t P_THIDB = 21732864;   // bf16 4096*384 ends 22,519,296
constexpr size_t P_TOK1B = 22519296;   // bf16 4096*768
constexpr size_t P_TOK2B = 24092160;   // bf16 4096*768
constexpr size_t P_QB    = 25665024;   // bf16 4096*768
constexpr size_t P_EEMB  = 27237888;   // bf16 768*Hm    ends 27,532,800
constexpr size_t P_PR0   = 27532800;   // f32 4096*768   ends 30,678,528
constexpr size_t P_PR0B  = 30678528;   // bf16 4096*768  ends 32,251,392
constexpr size_t P_PHIDB = 32251392;   // bf16 4096*384  ends 33,037,824
// whole-launch small weights (never read by the final GEMM)
constexpr size_t P_WT    = 74000000;   // ends 75,474,560 < 75,497,472
constexpr size_t S_ROOT  = 0;
constexpr size_t S_EP1A  = 147456;
constexpr size_t S_EP1B  = 221184;
constexpr size_t S_EP2   = 294912;
constexpr size_t S_TP1A  = 589824;
constexpr size_t S_TP1B  = 884736;
constexpr size_t S_TP2   = 1179648;
constexpr size_t S_CAW   = 1769472;
constexpr size_t S_PP1A  = 2359296;
constexpr size_t S_PP1B  = 2654208;

// ---------------- d_ws layout (bytes) ----------------
constexpr size_t WI       = 6291456 / 4;
constexpr size_t I_CNT    = WI + 0;
constexpr size_t I_PART   = WI + 30000;
constexpr size_t I_KG_RP  = WI + 30256;
constexpr size_t I_KG_CUR = WI + 60256;
constexpr size_t I_KG_SL  = WI + 90256;
constexpr size_t I_C_RP   = WI + 290256;
constexpr size_t I_C_CUR  = WI + 320256;
constexpr size_t I_C_SL   = WI + 350256;
constexpr size_t I_TS_RP  = WI + 550256;
constexpr size_t I_TS_CUR = WI + 556256;
constexpr size_t I_TS_SL  = WI + 562256;
constexpr size_t I_IS_RP  = WI + 642256;
constexpr size_t I_IS_CUR = WI + 648256;
constexpr size_t I_IS_SL  = WI + 654256;       // ends byte 9,228,480
constexpr size_t WS_PP2T_BYTE = 6291456;
constexpr size_t WS_NEED      = 34603008;

inline int cdiv(long a, long b) { return (int)((a + b - 1) / b); }

} // namespace

typedef short short8v __attribute__((ext_vector_type(8)));
typedef float f32x4 __attribute__((ext_vector_type(4)));

__device__ __forceinline__ unsigned short f2bf(float f) {
  union { float f; uint32_t u; } v; v.f = f;
  uint32_t u = v.u;
  u += 0x7fffu + ((u >> 16) & 1u);
  return (unsigned short)(u >> 16);
}
__device__ __forceinline__ uint32_t pkbf(float a, float b) {
  __hip_bfloat162 h = __float22bfloat162_rn(float2{a, b});
  union { __hip_bfloat162 h; uint32_t u; } cv; cv.h = h;
  return cv.u;
}
__device__ __forceinline__ float bflo(uint32_t u) {
  union { uint32_t u; float f; } c; c.u = u << 16; return c.f;
}
__device__ __forceinline__ float bfhi(uint32_t u) {
  union { uint32_t u; float f; } c; c.u = u & 0xFFFF0000u; return c.f;
}

__device__ __forceinline__ void gl16(const void* g, void* l) {
  __builtin_amdgcn_global_load_lds(
      (const __attribute__((address_space(1))) void*)g,
      (__attribute__((address_space(3))) void*)l, 16, 0, 0);
}

// ---------------------------------------------------------------------------
// conversion / utility kernels
// ---------------------------------------------------------------------------

__global__ void k_cvt(const float* __restrict__ x, unsigned short* __restrict__ o, size_t n2) {
  size_t i = (size_t)blockIdx.x * 256 + threadIdx.x;
  if (i >= n2) return;
  float2 v = *(const float2*)(x + 2 * i);
  *(uint32_t*)(o + 2 * i) = pkbf(v.x, v.y);
}

// f32 W[K][N] -> bf16 Wt[N][K]
__global__ void k_cvt_t(const float* __restrict__ W, unsigned short* __restrict__ Wt,
                        int K, int N) {
  __shared__ float t[32][33];
  int tx = threadIdx.x & 31, ty = threadIdx.x >> 5;
  int n0 = blockIdx.x * 32, k0 = blockIdx.y * 32;
#pragma unroll
  for (int j = 0; j < 4; ++j)
    t[ty + 8 * j][tx] = W[(size_t)(k0 + ty + 8 * j) * N + n0 + tx];
  __syncthreads();
#pragma unroll
  for (int j = 0; j < 4; ++j) {
    int n = ty + 8 * j;
    Wt[(size_t)(n0 + n) * K + k0 + tx] = f2bf(t[tx][n]);
  }
}

// wcat_t[(r*384+o)*384 + i] = sum_b comp[r][b]*bases[b][i][o]  (bf16)
__global__ void k_wcat(const float* __restrict__ comp, const float* __restrict__ bases,
                       unsigned short* __restrict__ Wt) {
  int idx = blockIdx.x * 256 + threadIdx.x;
  if (idx >= 12 * Dm * Dm) return;
  int i = idx % Dm;
  int o = (idx / Dm) % Dm;
  int r = idx / (Dm * Dm);
  float s = 0.f;
#pragma unroll
  for (int b = 0; b < 8; ++b)
    s += comp[r * 8 + b] * bases[(size_t)b * Dm * Dm + (size_t)i * Dm + o];
  Wt[idx] = f2bf(s);
}

// gather bf16 rows as u32 chunks
__global__ void k_gather_b(const int* __restrict__ idx, const uint32_t* __restrict__ x2,
                           uint32_t* __restrict__ out2, int rows, int D2) {
  size_t i = (size_t)blockIdx.x * 256 + threadIdx.x;
  if (i >= (size_t)rows * D2) return;
  int r = (int)(i / D2);
  int c = (int)(i - (size_t)r * D2);
  out2[i] = x2[(size_t)idx[r] * D2 + c];
}

// ent[mte[m]][d] += 0.25*g[m][d]
__global__ void k_scatter_movie(const int* __restrict__ mte, const float* __restrict__ g,
                                float* __restrict__ ent) {
  size_t i = (size_t)blockIdx.x * 256 + threadIdx.x;
  if (i >= MBF) return;
  int m = (int)(i / Dm);
  int d = (int)(i - (size_t)m * Dm);
  atomicAdd(&ent[(size_t)mte[m] * Dm + d], 0.25f * g[i]);
}

// ---------------------------------------------------------------------------
// CSR build
// ---------------------------------------------------------------------------

__global__ void k_hist(const int* __restrict__ dst, int* __restrict__ cnt, int E) {
  int e = blockIdx.x * 256 + threadIdx.x;
  if (e < E) atomicAdd(&cnt[dst[e]], 1);
}

__global__ void k_scan_blk(const int* __restrict__ in, int* __restrict__ out,
                           int* __restrict__ part, int n) {
  __shared__ int s[256];
  int t = threadIdx.x;
  int g = blockIdx.x * 256 + t;
  int v = (g < n) ? in[g] : 0;
  s[t] = v;
  __syncthreads();
  for (int off = 1; off < 256; off <<= 1) {
    int add = (t >= off) ? s[t - off] : 0;
    __syncthreads();
    s[t] += add;
    __syncthreads();
  }
  if (g < n) out[g] = s[t] - v;
  if (t == 255) part[blockIdx.x] = s[255];
}

__global__ void k_scan_top(int* __restrict__ part, int nb) {
  __shared__ int s[256];
  int t = threadIdx.x;
  int v = (t < nb) ? part[t] : 0;
  s[t] = v;
  __syncthreads();
  for (int off = 1; off < 256; off <<= 1) {
    int add = (t >= off) ? s[t - off] : 0;
    __syncthreads();
    s[t] += add;
    __syncthreads();
  }
  if (t < nb) part[t] = s[t] - v;
}

__global__ void k_scan_add(int* __restrict__ out, const int* __restrict__ part, int n) {
  int g = blockIdx.x * 256 + threadIdx.x;
  if (g < n) out[g] += part[blockIdx.x];
}

__global__ void k_fill(const int* __restrict__ src, const int* __restrict__ dst,
                       const int* __restrict__ typ, int* __restrict__ cur,
                       int* __restrict__ slots, int E) {
  int e = blockIdx.x * 256 + threadIdx.x;
  if (e >= E) return;
  int d = dst[e];
  int pos = atomicAdd(&cur[d], 1);
  int v = src[e];
  if (typ) v |= (typ[e] << 16);
  slots[pos] = v;
}

__global__ void k_dis_rp(const int* __restrict__ rp, float* __restrict__ dis, int n, int E) {
  int v = blockIdx.x * 256 + threadIdx.x;
  if (v >= n) return;
  int e0 = rp[v], e1 = (v + 1 < n) ? rp[v + 1] : E;
  dis[v] = rsqrtf((float)(e1 - e0) + 1.0f);
}

__global__ void k_count_type(const int* __restrict__ dst, const int* __restrict__ typ,
                             float* __restrict__ cnt, int E) {
  int i = blockIdx.x * 256 + threadIdx.x;
  if (i < E) atomicAdd(&cnt[(size_t)typ[i] * NE + dst[i]], 1.0f);
}

__global__ void k_rcp(float* __restrict__ c, size_t n) {
  size_t i = (size_t)blockIdx.x * 256 + threadIdx.x;
  if (i < n) { float v = c[i]; c[i] = (v > 0.f) ? 1.0f / v : 0.f; }
}

// ---------------------------------------------------------------------------
// bf16 gather kernel: one wave per dst row; a = dv*(dv*x[v] + sum dis[s]*x[s]).
// OUTM: 0 none, 1 outb = bf16(a) (raw gather result), 2 outb = bf16(acc_new).
// ACCM: 1 acc += sc*a; 2 acc = sc*(x[v]+a); 3 acc = sc*a.
// ---------------------------------------------------------------------------
template <int OUTM, int ACCM>
__global__ void k_gcn_gb(const unsigned short* __restrict__ x,
                         const float* __restrict__ dis,
                         const int* __restrict__ rp, const int* __restrict__ slots,
                         unsigned short* __restrict__ outb, float* __restrict__ acc,
                         int n, int E, float sc) {
  int v = (int)((blockIdx.x * (size_t)blockDim.x + threadIdx.x) >> 6);
  int lane = threadIdx.x & 63;
  if (v >= n) return;
  float dv = dis[v];
  const uint32_t* xr = (const uint32_t*)(x + (size_t)v * Dm);
  float xv[6];
#pragma unroll
  for (int i = 0; i < 3; ++i) {
    uint32_t u = xr[lane + 64 * i];
    xv[2 * i] = bflo(u); xv[2 * i + 1] = bfhi(u);
  }
  float a[6];
#pragma unroll
  for (int i = 0; i < 6; ++i) a[i] = dv * xv[i];
  int e0 = rp[v], e1 = (v + 1 < n) ? rp[v + 1] : E;
  for (int e = e0; e < e1; ++e) {
    int s = slots[e];
    float c = dis[s];
    const uint32_t* xs = (const uint32_t*)(x + (size_t)s * Dm);
#pragma unroll
    for (int i = 0; i < 3; ++i) {
      uint32_t u = xs[lane + 64 * i];
      a[2 * i]     = fmaf(c, bflo(u), a[2 * i]);
      a[2 * i + 1] = fmaf(c, bfhi(u), a[2 * i + 1]);
    }
  }
#pragma unroll
  for (int i = 0; i < 6; ++i) a[i] *= dv;
  if (OUTM == 1) {
    uint32_t* ob = (uint32_t*)(outb + (size_t)v * Dm);
#pragma unroll
    for (int i = 0; i < 3; ++i) ob[lane + 64 * i] = pkbf(a[2 * i], a[2 * i + 1]);
  }
  float* ar = acc + (size_t)v * Dm;
  float nw[6];
#pragma unroll
  for (int i = 0; i < 3; ++i) {
    int cidx = 2 * (lane + 64 * i);
    if (ACCM == 1) {
      float2 old = *(const float2*)(ar + cidx);
      nw[2 * i] = old.x + sc * a[2 * i];
      nw[2 * i + 1] = old.y + sc * a[2 * i + 1];
    } else if (ACCM == 2) {
      nw[2 * i] = sc * (xv[2 * i] + a[2 * i]);
      nw[2 * i + 1] = sc * (xv[2 * i + 1] + a[2 * i + 1]);
    } else {
      nw[2 * i] = sc * a[2 * i];
      nw[2 * i + 1] = sc * a[2 * i + 1];
    }
    *(float2*)(ar + cidx) = float2{nw[2 * i], nw[2 * i + 1]};
  }
  if (OUTM == 2) {
    uint32_t* ob = (uint32_t*)(outb + (size_t)v * Dm);
#pragma unroll
    for (int i = 0; i < 3; ++i) ob[lane + 64 * i] = pkbf(nw[2 * i], nw[2 * i + 1]);
  }
}

// ent0[v] += sum_{e: rbase<=r<rbase+6} rcp[r][v] * hh[src][(r-rbase)*384 + c]
// EMITB: also write ent0b = bf16(ent0) (used on the LAST call).
template <bool EMITB>
__global__ void k_rgcn_g(const unsigned short* __restrict__ hh, const float* __restrict__ rcp,
                         const int* __restrict__ rp, const int* __restrict__ slots,
                         float* __restrict__ ent0, unsigned short* __restrict__ outb,
                         int rbase, int E) {
  int v = (int)((blockIdx.x * (size_t)blockDim.x + threadIdx.x) >> 6);
  int lane = threadIdx.x & 63;
  if (v >= NE) return;
  int e0 = rp[v], e1 = (v + 1 < NE) ? rp[v + 1] : E;
  float* er = ent0 + (size_t)v * Dm;
  float2 a[3];
#pragma unroll
  for (int i = 0; i < 3; ++i) a[i] = *(const float2*)(er + 2 * lane + 128 * i);
  for (int e = e0; e < e1; ++e) {
    int p = slots[e];
    int r = p >> 16, s = p & 0xFFFF;
    if (r < rbase || r >= rbase + 6) continue;
    float nm = rcp[(size_t)r * NE + v];
    const unsigned short* hr = hh + (size_t)s * 2304 + (size_t)(r - rbase) * 384;
#pragma unroll
    for (int i = 0; i < 3; ++i) {
      uint32_t u = *(const uint32_t*)(hr + 2 * lane + 128 * i);
      a[i].x = fmaf(nm, bflo(u), a[i].x);
      a[i].y = fmaf(nm, bfhi(u), a[i].y);
    }
  }
#pragma unroll
  for (int i = 0; i < 3; ++i) *(float2*)(er + 2 * lane + 128 * i) = a[i];
  if (EMITB) {
    uint32_t* ob = (uint32_t*)(outb + (size_t)v * Dm);
#pragma unroll
    for (int i = 0; i < 3; ++i) ob[lane + 64 * i] = pkbf(a[i].x, a[i].y);
  }
}

// ---------------------------------------------------------------------------
// bf16 MFMA GEMM, 128x128 (m97 structure). A[M][K], Wt[N][K] bf16.
// OUT: 0 = f32 C, 1 = bf16 C, 2 = f32 transposed prompt layout.
// ---------------------------------------------------------------------------
template <bool RELU, bool RES, int OUT>
__global__ __launch_bounds__(256) void mgemm_bf(
    const unsigned short* __restrict__ A, const unsigned short* __restrict__ Wt,
    const float* __restrict__ bias, const float* __restrict__ Rp,
    void* __restrict__ Cv, int M, int N, int K) {
  __shared__ __align__(16) unsigned short As[128 * 64];
  __shared__ __align__(16) unsigned short Bs[128 * 64];
  const int tid = threadIdx.x;
  const int lane = tid & 63;
  const int w = tid >> 6;
  const int bm = blockIdx.x * 128, bn = blockIdx.y * 128;
  const int wr = (w >> 1) * 64, wc = (w & 1) * 64;
  const int lrow = lane & 15, lq = lane >> 4;
  f32x4 acc[4][4] = {};
  const int prow_l = lane >> 3;
  const int pslot = lane & 7;

  for (int k0 = 0; k0 < K; k0 += 64) {
    __syncthreads();
#pragma unroll
    for (int j = 0; j < 4; ++j) {
      int seg = j * 4 + w;
      int prow = seg * 8 + prow_l;
      int aslot = pslot ^ (prow & 7);
      int arow = min(bm + prow, M - 1);
      gl16(A + (size_t)arow * K + k0 + aslot * 8, &As[seg * 512 + lane * 8]);
    }
#pragma unroll
    for (int j = 0; j < 4; ++j) {
      int seg = j * 4 + w;
      int prow = seg * 8 + prow_l;
      int bslot = pslot ^ (prow & 7);
      int brow = min(bn + prow, N - 1);
      gl16(Wt + (size_t)brow * K + k0 + bslot * 8, &Bs[seg * 512 + lane * 8]);
    }
    __syncthreads();
#pragma unroll
    for (int ks = 0; ks < 2; ++ks) {
      short8v af[4], bf[4];
      const int slot = ks * 4 + lq;
#pragma unroll
      for (int mr = 0; mr < 4; ++mr) {
        int r = wr + mr * 16 + lrow;
        af[mr] = *(const short8v*)&As[r * 64 + ((slot ^ (r & 7)) << 3)];
      }
#pragma unroll
      for (int nc = 0; nc < 4; ++nc) {
        int r = wc + nc * 16 + lrow;
        bf[nc] = *(const short8v*)&Bs[r * 64 + ((slot ^ (r & 7)) << 3)];
      }
#pragma unroll
      for (int mr = 0; mr < 4; ++mr)
#pragma unroll
        for (int nc = 0; nc < 4; ++nc)
          acc[mr][nc] = __builtin_amdgcn_mfma_f32_16x16x32_bf16(
              af[mr], bf[nc], acc[mr][nc], 0, 0, 0);
    }
  }
#pragma unroll
  for (int mr = 0; mr < 4; ++mr) {
#pragma unroll
    for (int e = 0; e < 4; ++e) {
      int r = bm + wr + mr * 16 + lq * 4 + e;
      if (r >= M) continue;
#pragma unroll
      for (int nc = 0; nc < 4; ++nc) {
        int c = bn + wc + nc * 16 + lrow;
        if (c >= N) continue;
        float v = acc[mr][nc][e];
        if (bias) v += bias[c];
        if (RES) v += Rp[(size_t)r * N + c];
        if (RELU) v = fmaxf(v, 0.f);
        if (OUT == 0) {
          ((float*)Cv)[(size_t)r * N + c] = v;
        } else if (OUT == 1) {
          ((unsigned short*)Cv)[(size_t)r * N + c] = f2bf(v);
        } else {
          int b = r >> 8, t = r & 255;
          int l = c / 1536, rem = c - l * 1536;
          int blk = rem / 768, rem2 = rem - blk * 768;
          int hh = rem2 >> 6, dd = rem2 & 63;
          size_t oi = (((((size_t)l * 2 + blk) * 16 + b) * 12 + hh) * 256 + t) * 64 + dd;
          ((float*)Cv)[oi] = v;
        }
      }
    }
  }
}

// Fallback FINAL GEMM (ws too small): W f32 from d_in, in-kernel conversion.
__global__ __launch_bounds__(256) void mgemm_fin(
    const unsigned short* __restrict__ A, const float* __restrict__ W,
    const float* __restrict__ bias, float* __restrict__ O, int M, int N, int K) {
  __shared__ __align__(16) unsigned short As[128 * 64];
  __shared__ __align__(16) unsigned short Bs[128 * 64];
  const int tid = threadIdx.x;
  const int lane = tid & 63;
  const int w = tid >> 6;
  const int bm = blockIdx.x * 128, bn = blockIdx.y * 128;
  const int wr = (w >> 1) * 64, wc = (w & 1) * 64;
  const int lrow = lane & 15, lq = lane >> 4;
  f32x4 acc[4][4] = {};
  const int prow_l = lane >> 3;
  const int pslot = lane & 7;
  const int n_loc = tid & 127;
  const int kh = (tid >> 7) * 32;

  for (int k0 = 0; k0 < K; k0 += 64) {
    __syncthreads();
#pragma unroll
    for (int j = 0; j < 4; ++j) {
      int seg = j * 4 + w;
      int prow = seg * 8 + prow_l;
      int aslot = pslot ^ (prow & 7);
      gl16(A + (size_t)(bm + prow) * K + k0 + aslot * 8, &As[seg * 512 + lane * 8]);
    }
    float wv[32];
    const float* wp = W + (size_t)(k0 + kh) * N + bn + n_loc;
#pragma unroll
    for (int j = 0; j < 32; ++j) wv[j] = wp[(size_t)j * N];
#pragma unroll
    for (int c = 0; c < 4; ++c) {
      uint32_t u0 = pkbf(wv[8 * c + 0], wv[8 * c + 1]);
      uint32_t u1 = pkbf(wv[8 * c + 2], wv[8 * c + 3]);
      uint32_t u2 = pkbf(wv[8 * c + 4], wv[8 * c + 5]);
      uint32_t u3 = pkbf(wv[8 * c + 6], wv[8 * c + 7]);
      int s = (kh >> 3) + c;
      *(uint4*)&Bs[n_loc * 64 + ((s ^ (n_loc & 7)) << 3)] = uint4{u0, u1, u2, u3};
    }
    __syncthreads();
#pragma unroll
    for (int ks = 0; ks < 2; ++ks) {
      short8v af[4], bf[4];
      const int slot = ks * 4 + lq;
#pragma unroll
      for (int mr = 0; mr < 4; ++mr) {
        int r = wr + mr * 16 + lrow;
        af[mr] = *(const short8v*)&As[r * 64 + ((slot ^ (r & 7)) << 3)];
      }
#pragma unroll
      for (int nc = 0; nc < 4; ++nc) {
        int r = wc + nc * 16 + lrow;
        bf[nc] = *(const short8v*)&Bs[r * 64 + ((slot ^ (r & 7)) << 3)];
      }
#pragma unroll
      for (int mr = 0; mr < 4; ++mr)
#pragma unroll
        for (int nc = 0; nc < 4; ++nc)
          acc[mr][nc] = __builtin_amdgcn_mfma_f32_16x16x32_bf16(
              af[mr], bf[nc], acc[mr][nc], 0, 0, 0);
    }
  }
#pragma unroll
  for (int mr = 0; mr < 4; ++mr) {
#pragma unroll
    for (int e = 0; e < 4; ++e) {
      int r = bm + wr + mr * 16 + lq * 4 + e;
      int b = r >> 8, t = r & 255;
#pragma unroll
      for (int nc = 0; nc < 4; ++nc) {
        int c = bn + wc + nc * 16 + lrow;
        float v = acc[mr][nc][e] + bias[c];
        int l = c / 1536, rem = c - l * 1536;
        int blk = rem / 768, rem2 = rem - blk * 768;
        int hh = rem2 >> 6, dd = rem2 & 63;
        size_t oi = (((((size_t)l * 2 + blk) * 16 + b) * 12 + hh) * 256 + t) * 64 + dd;
        O[oi] = v;
      }
    }
  }
}

// ---------------------------------------------------------------------------
// fused cross-attention (bf16 inputs): one wave per (b,t)
// ---------------------------------------------------------------------------
__global__ __launch_bounds__(256) void k_attn(
    const unsigned short* __restrict__ qb, const unsigned short* __restrict__ eb_all,
    const unsigned short* __restrict__ tokb, float* __restrict__ pr0,
    unsigned short* __restrict__ pr0b) {
  int gw = (int)((blockIdx.x * (size_t)blockDim.x + threadIdx.x) >> 6);
  int lane = threadIdx.x & 63;
  if (gw >= NTOK) return;
  int b = gw >> 8;
  const unsigned short* qr = qb + (size_t)gw * Hm;
  float2 q[6];
#pragma unroll
  for (int i = 0; i < 6; ++i) {
    uint32_t u = *(const uint32_t*)(qr + 2 * lane + 128 * i);
    q[i] = float2{bflo(u), bfhi(u)};
  }
  const unsigned short* eb = eb_all + (size_t)b * LE * Hm;
  float myA = -3.0e38f;
  for (int e = 0; e < LE; ++e) {
    const unsigned short* er = eb + (size_t)e * Hm;
    float s = 0.f;
#pragma unroll
    for (int i = 0; i < 6; ++i) {
      uint32_t u = *(const uint32_t*)(er + 2 * lane + 128 * i);
      s = fmaf(q[i].x, bflo(u), s);
      s = fmaf(q[i].y, bfhi(u), s);
    }
#pragma unroll
    for (int off = 32; off > 0; off >>= 1) s += __shfl_xor(s, off);
    if (lane == e) myA = s * (1.0f / 768.0f);
  }
  float mx = myA;
#pragma unroll
  for (int off = 32; off > 0; off >>= 1) mx = fmaxf(mx, __shfl_xor(mx, off));
  float p = (lane < LE) ? expf(myA - mx) : 0.f;
  float sum = p;
#pragma unroll
  for (int off = 32; off > 0; off >>= 1) sum += __shfl_xor(sum, off);
  float wgt = p / sum;
  const unsigned short* tr = tokb + (size_t)gw * Hm;
  float2 a[6];
#pragma unroll
  for (int i = 0; i < 6; ++i) {
    uint32_t u = *(const uint32_t*)(tr + 2 * lane + 128 * i);
    a[i] = float2{bflo(u), bfhi(u)};
  }
  for (int e = 0; e < LE; ++e) {
    float we = __shfl(wgt, e);
    const unsigned short* er = eb + (size_t)e * Hm;
#pragma unroll
    for (int i = 0; i < 6; ++i) {
      uint32_t u = *(const uint32_t*)(er + 2 * lane + 128 * i);
      a[i].x = fmaf(we, bflo(u), a[i].x);
      a[i].y = fmaf(we, bfhi(u), a[i].y);
    }
  }
  float* orow = pr0 + (size_t)gw * Hm;
  unsigned short* obrow = pr0b + (size_t)gw * Hm;
#pragma unroll
  for (int i = 0; i < 6; ++i) {
    *(float2*)(orow + 2 * lane + 128 * i) = a[i];
    *(uint32_t*)(obrow + 2 * lane + 128 * i) = pkbf(a[i].x, a[i].y);
  }
}

// ---------------------------------------------------------------------------

extern "C" void kernel_launch(void* const* d_in, const int* in_sizes, int n_in,
                              void* d_out, int out_size, void* d_ws, size_t ws_size,
                              hipStream_t stream) {
  (void)in_sizes; (void)n_in; (void)out_size;

  const float* x_node = (const float*)d_in[0];
  const float* bases  = (const float*)d_in[1];
  const float* comp   = (const float*)d_in[2];
  const float* root   = (const float*)d_in[3];
  const float* rbias  = (const float*)d_in[4];
  const float* ep1w1  = (const float*)d_in[5];
  const float* ep1b1  = (const float*)d_in[6];
  const float* ep1w2  = (const float*)d_in[7];
  const float* ep1b2  = (const float*)d_in[8];
  const float* ep2w   = (const float*)d_in[9];
  const float* ep2b   = (const float*)d_in[10];
  const float* tp1w1  = (const float*)d_in[11];
  const float* tp1b1  = (const float*)d_in[12];
  const float* tp1w2  = (const float*)d_in[13];
  const float* tp1b2  = (const float*)d_in[14];
  const float* tp2w   = (const float*)d_in[15];
  const float* tp2b   = (const float*)d_in[16];
  const float* caw    = (const float*)d_in[17];
  const float* pp1w1  = (const float*)d_in[18];
  const float* pp1b1  = (const float*)d_in[19];
  const float* pp1w2  = (const float*)d_in[20];
  const float* pp1b2  = (const float*)d_in[21];
  const float* pp2w   = (const float*)d_in[22];
  const float* pp2b   = (const float*)d_in[23];
  const float* tokens = (const float*)d_in[24];
  const int* ei_kg = (const int*)d_in[25];
  const int* etype = (const int*)d_in[26];
  const int* ei_c  = (const int*)d_in[27];
  const int* ei_ts = (const int*)d_in[28];
  const int* ei_is = (const int*)d_in[29];
  const int* mte   = (const int*)d_in[30];
  const int* eids  = (const int*)d_in[31];

  float* O = (float*)d_out;
  unsigned short* xb    = (unsigned short*)(O + P_XB);
  unsigned short* wct   = (unsigned short*)(O + P_WCT);
  float* rcpc  = O + P_CNT;
  float* ent0  = O + P_ENT0;
  unsigned short* hh    = (unsigned short*)(O + P_HH);
  float* disc  = O + P_DIS;
  float* dist  = O + P_DIS + 30000;
  float* disi  = O + P_DIS + 36000;
  unsigned short* ent0b = (unsigned short*)(O + P_E0B);
  unsigned short* c1b   = (unsigned short*)(O + P_C1B);
  unsigned short* c2b   = (unsigned short*)(O + P_C2B);
  unsigned short* nfb   = (unsigned short*)(O + P_NFB);
  unsigned short* t1b   = (unsigned short*)(O + P_T1B);
  float* g1    = O + P_G1;
  float* accb  = O + P_ACC;
  unsigned short* entb  = (unsigned short*)(O + P_ENTB);
  unsigned short* hidb  = (unsigned short*)(O + P_HIDB);
  unsigned short* ent2b = (unsigned short*)(O + P_ENT2B);
  unsigned short* e768b = (unsigned short*)(O + P_E768B);
  unsigned short* tokb  = (unsigned short*)(O + P_TOKB);
  unsigned short* thidb = (unsigned short*)(O + P_THIDB);
  unsigned short* tok1b = (unsigned short*)(O + P_TOK1B);
  unsigned short* tok2b = (unsigned short*)(O + P_TOK2B);
  unsigned short* qb    = (unsigned short*)(O + P_QB);
  unsigned short* eemb  = (unsigned short*)(O + P_EEMB);
  float* pr0   = O + P_PR0;
  unsigned short* pr0b  = (unsigned short*)(O + P_PR0B);
  unsigned short* phidb = (unsigned short*)(O + P_PHIDB);
  unsigned short* wts   = (unsigned short*)(O + P_WT);

  int* iws = (int*)d_ws;
  unsigned short* p2b = (unsigned short*)d_ws;
  unsigned short* pp2t = (unsigned short*)d_ws + WS_PP2T_BYTE / 2;
  const bool ws_ok = (ws_size >= WS_NEED);
  int* cnt_i  = iws + I_CNT;
  int* part   = iws + I_PART;
  int* kg_rp  = iws + I_KG_RP;  int* kg_cur = iws + I_KG_CUR;  int* kg_sl = iws + I_KG_SL;
  int* c_rp   = iws + I_C_RP;   int* c_cur  = iws + I_C_CUR;   int* c_sl  = iws + I_C_SL;
  int* ts_rp  = iws + I_TS_RP;  int* ts_cur = iws + I_TS_CUR;  int* ts_sl = iws + I_TS_SL;
  int* is_rp  = iws + I_IS_RP;  int* is_cur = iws + I_IS_CUR;  int* is_sl = iws + I_IS_SL;

  const int EW = 256;

  // ---------------- phase A: conversions ----------------
  k_cvt<<<cdiv(NBf / 2, EW), EW, 0, stream>>>(x_node, xb, NBf / 2);
  k_wcat<<<cdiv(12 * Dm * Dm, EW), EW, 0, stream>>>(comp, bases, wct);
  k_cvt_t<<<dim3(Dm / 32, Dm / 32), 256, 0, stream>>>(root, wts + S_ROOT, Dm, Dm);
  k_cvt_t<<<dim3(192 / 32, Dm / 32), 256, 0, stream>>>(ep1w1, wts + S_EP1A, Dm, 192);
  k_cvt_t<<<dim3(Dm / 32, 192 / 32), 256, 0, stream>>>(ep1w2, wts + S_EP1B, 192, Dm);
  k_cvt_t<<<dim3(Hm / 32, Dm / 32), 256, 0, stream>>>(ep2w, wts + S_EP2, Dm, Hm);
  k_cvt_t<<<dim3(Dm / 32, Hm / 32), 256, 0, stream>>>(tp1w1, wts + S_TP1A, Hm, Dm);
  k_cvt_t<<<dim3(Hm / 32, Dm / 32), 256, 0, stream>>>(tp1w2, wts + S_TP1B, Dm, Hm);
  k_cvt_t<<<dim3(Hm / 32, Hm / 32), 256, 0, stream>>>(tp2w, wts + S_TP2, Hm, Hm);
  k_cvt_t<<<dim3(Hm / 32, Hm / 32), 256, 0, stream>>>(caw, wts + S_CAW, Hm, Hm);
  k_cvt_t<<<dim3(Dm / 32, Hm / 32), 256, 0, stream>>>(pp1w1, wts + S_PP1A, Hm, Dm);
  k_cvt_t<<<dim3(Hm / 32, Dm / 32), 256, 0, stream>>>(pp1w2, wts + S_PP1B, Dm, Hm);

  // ---------------- CSR builds ----------------
  auto build_csr = [&](const int* ei, const int* typ, int n, int E,
                       int* rp, int* cur, int* sl) {
    hipMemsetAsync(cnt_i, 0, (size_t)n * 4, stream);
    k_hist<<<cdiv(E, EW), EW, 0, stream>>>(ei + E, cnt_i, E);
    int nb = cdiv(n, 256);
    k_scan_blk<<<nb, 256, 0, stream>>>(cnt_i, rp, part, n);
    k_scan_top<<<1, 256, 0, stream>>>(part, nb);
    k_scan_add<<<nb, 256, 0, stream>>>(rp, part, n);
    hipMemcpyAsync(cur, rp, (size_t)n * 4, hipMemcpyDeviceToDevice, stream);
    k_fill<<<cdiv(E, EW), EW, 0, stream>>>(ei, ei + E, typ, cur, sl, E);
  };
  build_csr(ei_kg, etype, NE, EKG, kg_rp, kg_cur, kg_sl);
  build_csr(ei_c, nullptr, NE, EC, c_rp, c_cur, c_sl);
  build_csr(ei_ts, nullptr, NM, ES, ts_rp, ts_cur, ts_sl);
  build_csr(ei_is, nullptr, NM, ES, is_rp, is_cur, is_sl);

  k_dis_rp<<<cdiv(NE, EW), EW, 0, stream>>>(c_rp, disc, NE, EC);
  k_dis_rp<<<cdiv(NM, EW), EW, 0, stream>>>(ts_rp, dist, NM, ES);
  k_dis_rp<<<cdiv(NM, EW), EW, 0, stream>>>(is_rp, disi, NM, ES);

  hipMemsetAsync(rcpc, 0, (size_t)12 * NE * 4, stream);
  k_count_type<<<cdiv(EKG, EW), EW, 0, stream>>>(ei_kg + EKG, etype, rcpc, EKG);
  k_rcp<<<cdiv((long)12 * NE, EW), EW, 0, stream>>>(rcpc, (size_t)12 * NE);

  // ---------------- RGCN ----------------
  mgemm_bf<false, true, 0><<<dim3(cdiv(NE, 128), cdiv(Dm, 128)), 256, 0, stream>>>(
      xb, wts + S_ROOT, rbias, x_node, ent0, NE, Dm, Dm);
  mgemm_bf<false, false, 1><<<dim3(cdiv(NE, 128), cdiv(6 * Dm, 128)), 256, 0, stream>>>(
      xb, wct, nullptr, nullptr, hh, NE, 6 * Dm, Dm);
  k_rgcn_g<false><<<cdiv((long)NE * 64, EW), EW, 0, stream>>>(
      hh, rcpc, kg_rp, kg_sl, ent0, nullptr, 0, EKG);
  mgemm_bf<false, false, 1><<<dim3(cdiv(NE, 128), cdiv(6 * Dm, 128)), 256, 0, stream>>>(
      xb, wct + (size_t)6 * Dm * Dm, nullptr, nullptr, hh, NE, 6 * Dm, Dm);
  // last RGCN gather also emits ent0b (bf16) — xb dead by now
  k_rgcn_g<true><<<cdiv((long)NE * 64, EW), EW, 0, stream>>>(
      hh, rcpc, kg_rp, kg_sl, ent0, ent0b, 6, EKG);

  // ---------------- phase B: graph chains (bf16) ----------------
  // movie branch: nfb = ent0b[mte]; g1 = ts1+ts2+is1+is2 (f32)
  k_gather_b<<<cdiv((long)NM * 192, EW), EW, 0, stream>>>(
      mte, (const uint32_t*)ent0b, (uint32_t*)nfb, NM, 192);
  k_gcn_gb<1, 3><<<cdiv((long)NM * 64, EW), EW, 0, stream>>>(
      nfb, dist, ts_rp, ts_sl, t1b, g1, NM, ES, 1.0f);
  k_gcn_gb<0, 1><<<cdiv((long)NM * 64, EW), EW, 0, stream>>>(
      t1b, dist, ts_rp, ts_sl, nullptr, g1, NM, ES, 1.0f);
  k_gcn_gb<1, 1><<<cdiv((long)NM * 64, EW), EW, 0, stream>>>(
      nfb, disi, is_rp, is_sl, t1b, g1, NM, ES, 1.0f);
  k_gcn_gb<0, 1><<<cdiv((long)NM * 64, EW), EW, 0, stream>>>(
      t1b, disi, is_rp, is_sl, nullptr, g1, NM, ES, 1.0f);
  // entity chain with folded 0.25: accb = 0.25*(ent0+c1) then += 0.25*c2,
  // += movie (scatter), then final pass += 0.25*c3 and emits entb bf16.
  k_gcn_gb<1, 2><<<cdiv((long)NE * 64, EW), EW, 0, stream>>>(
      ent0b, disc, c_rp, c_sl, c1b, accb, NE, EC, 0.25f);
  k_gcn_gb<1, 1><<<cdiv((long)NE * 64, EW), EW, 0, stream>>>(
      c1b, disc, c_rp, c_sl, c2b, accb, NE, EC, 0.25f);
  k_scatter_movie<<<cdiv(MBF, EW), EW, 0, stream>>>(mte, g1, accb);
  k_gcn_gb<2, 1><<<cdiv((long)NE * 64, EW), EW, 0, stream>>>(
      c2b, disc, c_rp, c_sl, entb, accb, NE, EC, 0.25f);

  // pp2t conversion (CSR arrays now dead)
  if (ws_ok) {
    k_cvt_t<<<dim3(NO / 32, Hm / 32), 256, 0, stream>>>(pp2w, pp2t, Hm, NO);
  }

  // ---------------- entity MLP ----------------
  mgemm_bf<true, false, 1><<<dim3(cdiv(NE, 128), cdiv(192, 128)), 256, 0, stream>>>(
      entb, wts + S_EP1A, ep1b1, nullptr, hidb, NE, 192, Dm);
  mgemm_bf<false, true, 1><<<dim3(cdiv(NE, 128), cdiv(Dm, 128)), 256, 0, stream>>>(
      hidb, wts + S_EP1B, ep1b2, accb, ent2b, NE, Dm, 192);
  mgemm_bf<false, false, 1><<<dim3(cdiv(NE, 128), cdiv(Hm, 128)), 256, 0, stream>>>(
      ent2b, wts + S_EP2, ep2b, nullptr, e768b, NE, Hm, Dm);

  // ---------------- token path ----------------
  k_cvt<<<cdiv((long)NTOK * Hm / 2, EW), EW, 0, stream>>>(tokens, tokb, (size_t)NTOK * Hm / 2);
  mgemm_bf<true, false, 1><<<dim3(cdiv(NTOK, 128), cdiv(Dm, 128)), 256, 0, stream>>>(
      tokb, wts + S_TP1A, tp1b1, nullptr, thidb, NTOK, Dm, Hm);
  mgemm_bf<false, true, 1><<<dim3(cdiv(NTOK, 128), cdiv(Hm, 128)), 256, 0, stream>>>(
      thidb, wts + S_TP1B, tp1b2, tokens, tok1b, NTOK, Hm, Dm);
  mgemm_bf<false, false, 1><<<dim3(cdiv(NTOK, 128), cdiv(Hm, 128)), 256, 0, stream>>>(
      tok1b, wts + S_TP2, tp2b, nullptr, tok2b, NTOK, Hm, Hm);
  mgemm_bf<false, false, 1><<<dim3(cdiv(NTOK, 128), cdiv(Hm, 128)), 256, 0, stream>>>(
      tok2b, wts + S_CAW, nullptr, nullptr, qb, NTOK, Hm, Hm);

  k_gather_b<<<cdiv((long)Bc * LE * (Hm / 2), EW), EW, 0, stream>>>(
      eids, (const uint32_t*)e768b, (uint32_t*)eemb, Bc * LE, Hm / 2);
  k_attn<<<cdiv((long)NTOK * 64, 256), 256, 0, stream>>>(qb, eemb, tok2b, pr0, pr0b);

  mgemm_bf<true, false, 1><<<dim3(cdiv(NTOK, 128), cdiv(Dm, 128)), 256, 0, stream>>>(
      pr0b, wts + S_PP1A, pp1b1, nullptr, phidb, NTOK, Dm, Hm);
  mgemm_bf<false, true, 1><<<dim3(cdiv(NTOK, 128), cdiv(Hm, 128)), 256, 0, stream>>>(
      phidb, wts + S_PP1B, pp1b2, pr0, p2b, NTOK, Hm, Dm);

  // ---------------- final GEMM + transpose (reads ONLY d_ws/d_in) ---------
  if (ws_ok) {
    mgemm_bf<false, false, 2><<<dim3(NTOK / 128, NO / 128), 256, 0, stream>>>(
        p2b, pp2t, pp2b, nullptr, O, NTOK, NO, Hm);
  } else {
    mgemm_fin<<<dim3(NTOK / 128, NO / 128), 256, 0, stream>>>(
        p2b, pp2w, pp2b, O, NTOK, NO, Hm);
  }
}

// Round 9
// 1637.646 us; speedup vs baseline: 1.2432x; 1.0028x over previous
//
#include <hip/hip_runtime.h>
#include <hip/hip_bf16.h>
#include <cstdint>
#include <cstddef>

// ---------------------------------------------------------------------------
// MMPrompt pipeline, round 9 (= r8 + gather-cluster optimization):
//  - 2-edge unrolled CSR gathers (doubled memory-level parallelism).
//  - KG CSR split per relation-half via per-node boundary (no filtering scan).
//  - GEMMs unchanged: proven mgemm_bf 128x128 m97 structure, 0 conflicts.
// ---------------------------------------------------------------------------

namespace {

constexpr int NE   = 30000;
constexpr int NM   = 6000;
constexpr int Dm   = 384;
constexpr int Hm   = 768;
constexpr int EKG  = 200000;
constexpr int EC   = 200000;
constexpr int ES   = 80000;
constexpr int Bc   = 16;
constexpr int LE   = 48;
constexpr int NTOK = 4096;
constexpr int NO   = 18432;

constexpr size_t NBf = (size_t)NE * Dm;   // 11,520,000
constexpr size_t MBF = (size_t)NM * Dm;   // 2,304,000

// ---------------- d_out arena (f32-unit offsets) ----------------
// phase A (conversions + RGCN)
constexpr size_t P_XB    = 0;          // xb bf16 NE*384           ends 5,760,000
constexpr size_t P_WCT   = 5760000;    // wcat_t bf16 12*384*384   ends 6,644,736
constexpr size_t P_CNT   = 6644736;    // rcp cnt f32 12*NE        ends 7,004,736
constexpr size_t P_ENT0  = 7004736;    // f32 NE*384               ends 18,524,736
constexpr size_t P_HH    = 18524736;   // h bf16 NE*2304           ends 53,084,736
constexpr size_t P_DIS   = 53084736;   // disc+dist+disi f32 42,000 ends 53,126,736
// phase B (graph chains) — xb dead after hh GEMM#2; ent0 dead after rgcn#2
constexpr size_t P_E0B   = 0;          // ent0b bf16 NE*384  ends 2,880,000
constexpr size_t P_C1B   = 2880000;    // bf16 NE*384        ends 5,760,000
constexpr size_t P_C2B   = 5760000;    // bf16 NE*384        ends 8,640,000
constexpr size_t P_NFB   = 8640000;    // bf16 NM*384        ends 9,792,000
constexpr size_t P_T1B   = 9800000;    // bf16 NM*384        ends 10,952,000
constexpr size_t P_G1    = 11000000;   // f32 NM*384         ends 13,304,000
constexpr size_t P_ACC   = 41564736;   // f32 NE*384 (over dead hh) ends 53,084,736
constexpr size_t P_ENTB  = 55600000;   // bf16 NE*384        ends 61,360,000
// phase C (MLP/token/attn) — all phase-B small buffers dead
constexpr size_t P_HIDB  = 0;          // bf16 NE*192   ends 1,440,000
constexpr size_t P_ENT2B = 2880000;    // bf16 NE*384   ends 8,640,000
constexpr size_t P_E768B = 8640000;    // bf16 NE*768   ends 20,160,000
constexpr size_t P_TOKB  = 20160000;   // bf16 4096*768 ends 21,732,864
constexpr size_t P_THIDB = 21732864;   // bf16 4096*384 ends 22,519,296
constexpr size_t P_TOK1B = 22519296;   // bf16 4096*768
constexpr size_t P_TOK2B = 24092160;   // bf16 4096*768
constexpr size_t P_QB    = 25665024;   // bf16 4096*768
constexpr size_t P_EEMB  = 27237888;   // bf16 768*Hm    ends 27,532,800
constexpr size_t P_PR0   = 27532800;   // f32 4096*768   ends 30,678,528
constexpr size_t P_PR0B  = 30678528;   // bf16 4096*768  ends 32,251,392
constexpr size_t P_PHIDB = 32251392;   // bf16 4096*384  ends 33,037,824
// whole-launch small weights (never read by the final GEMM)
constexpr size_t P_WT    = 74000000;   // ends 75,474,560 < 75,497,472
constexpr size_t S_ROOT  = 0;
constexpr size_t S_EP1A  = 147456;
constexpr size_t S_EP1B  = 221184;
constexpr size_t S_EP2   = 294912;
constexpr size_t S_TP1A  = 589824;
constexpr size_t S_TP1B  = 884736;
constexpr size_t S_TP2   = 1179648;
constexpr size_t S_CAW   = 1769472;
constexpr size_t S_PP1A  = 2359296;
constexpr size_t S_PP1B  = 2654208;

// ---------------- d_ws layout (bytes) ----------------
constexpr size_t WI       = 6291456 / 4;
constexpr size_t I_CNT    = WI + 0;
constexpr size_t I_PART   = WI + 30000;
constexpr size_t I_KG_RP  = WI + 30256;
constexpr size_t I_KG_CA  = WI + 60256;   // cur for r<6 half
constexpr size_t I_KG_SL  = WI + 90256;
constexpr size_t I_C_RP   = WI + 290256;
constexpr size_t I_C_CUR  = WI + 320256;
constexpr size_t I_C_SL   = WI + 350256;
constexpr size_t I_TS_RP  = WI + 550256;
constexpr size_t I_TS_CUR = WI + 556256;
constexpr size_t I_TS_SL  = WI + 562256;
constexpr size_t I_IS_RP  = WI + 642256;
constexpr size_t I_IS_CUR = WI + 648256;
constexpr size_t I_IS_SL  = WI + 654256;  // ends WI+734,256
constexpr size_t I_KG_BND = WI + 734256;  // 30000
constexpr size_t I_KG_CB  = WI + 764256;  // 30000 -> ends WI+794,256 (~9.5MB)
constexpr size_t WS_PP2T_BYTE = 6291456;  // overlays CSR after its death
constexpr size_t WS_NEED      = 34603008;

inline int cdiv(long a, long b) { return (int)((a + b - 1) / b); }

} // namespace

typedef short short8v __attribute__((ext_vector_type(8)));
typedef float f32x4 __attribute__((ext_vector_type(4)));

__device__ __forceinline__ unsigned short f2bf(float f) {
  union { float f; uint32_t u; } v; v.f = f;
  uint32_t u = v.u;
  u += 0x7fffu + ((u >> 16) & 1u);
  return (unsigned short)(u >> 16);
}
__device__ __forceinline__ uint32_t pkbf(float a, float b) {
  __hip_bfloat162 h = __float22bfloat162_rn(float2{a, b});
  union { __hip_bfloat162 h; uint32_t u; } cv; cv.h = h;
  return cv.u;
}
__device__ __forceinline__ float bflo(uint32_t u) {
  union { uint32_t u; float f; } c; c.u = u << 16; return c.f;
}
__device__ __forceinline__ float bfhi(uint32_t u) {
  union { uint32_t u; float f; } c; c.u = u & 0xFFFF0000u; return c.f;
}

__device__ __forceinline__ void gl16(const void* g, void* l) {
  __builtin_amdgcn_global_load_lds(
      (const __attribute__((address_space(1))) void*)g,
      (__attribute__((address_space(3))) void*)l, 16, 0, 0);
}

// ---------------------------------------------------------------------------
// conversion / utility kernels
// ---------------------------------------------------------------------------

__global__ void k_cvt(const float* __restrict__ x, unsigned short* __restrict__ o, size_t n2) {
  size_t i = (size_t)blockIdx.x * 256 + threadIdx.x;
  if (i >= n2) return;
  float2 v = *(const float2*)(x + 2 * i);
  *(uint32_t*)(o + 2 * i) = pkbf(v.x, v.y);
}

// f32 W[K][N] -> bf16 Wt[N][K]
__global__ void k_cvt_t(const float* __restrict__ W, unsigned short* __restrict__ Wt,
                        int K, int N) {
  __shared__ float t[32][33];
  int tx = threadIdx.x & 31, ty = threadIdx.x >> 5;
  int n0 = blockIdx.x * 32, k0 = blockIdx.y * 32;
#pragma unroll
  for (int j = 0; j < 4; ++j)
    t[ty + 8 * j][tx] = W[(size_t)(k0 + ty + 8 * j) * N + n0 + tx];
  __syncthreads();
#pragma unroll
  for (int j = 0; j < 4; ++j) {
    int n = ty + 8 * j;
    Wt[(size_t)(n0 + n) * K + k0 + tx] = f2bf(t[tx][n]);
  }
}

// wcat_t[(r*384+o)*384 + i] = sum_b comp[r][b]*bases[b][i][o]  (bf16)
__global__ void k_wcat(const float* __restrict__ comp, const float* __restrict__ bases,
                       unsigned short* __restrict__ Wt) {
  int idx = blockIdx.x * 256 + threadIdx.x;
  if (idx >= 12 * Dm * Dm) return;
  int i = idx % Dm;
  int o = (idx / Dm) % Dm;
  int r = idx / (Dm * Dm);
  float s = 0.f;
#pragma unroll
  for (int b = 0; b < 8; ++b)
    s += comp[r * 8 + b] * bases[(size_t)b * Dm * Dm + (size_t)i * Dm + o];
  Wt[idx] = f2bf(s);
}

// gather bf16 rows as u32 chunks
__global__ void k_gather_b(const int* __restrict__ idx, const uint32_t* __restrict__ x2,
                           uint32_t* __restrict__ out2, int rows, int D2) {
  size_t i = (size_t)blockIdx.x * 256 + threadIdx.x;
  if (i >= (size_t)rows * D2) return;
  int r = (int)(i / D2);
  int c = (int)(i - (size_t)r * D2);
  out2[i] = x2[(size_t)idx[r] * D2 + c];
}

// ent[mte[m]][d] += 0.25*g[m][d]
__global__ void k_scatter_movie(const int* __restrict__ mte, const float* __restrict__ g,
                                float* __restrict__ ent) {
  size_t i = (size_t)blockIdx.x * 256 + threadIdx.x;
  if (i >= MBF) return;
  int m = (int)(i / Dm);
  int d = (int)(i - (size_t)m * Dm);
  atomicAdd(&ent[(size_t)mte[m] * Dm + d], 0.25f * g[i]);
}

// ---------------------------------------------------------------------------
// CSR build
// ---------------------------------------------------------------------------

__global__ void k_hist(const int* __restrict__ dst, int* __restrict__ cnt, int E) {
  int e = blockIdx.x * 256 + threadIdx.x;
  if (e < E) atomicAdd(&cnt[dst[e]], 1);
}

__global__ void k_hist_lt(const int* __restrict__ dst, const int* __restrict__ typ,
                          int* __restrict__ cnt, int E) {
  int e = blockIdx.x * 256 + threadIdx.x;
  if (e < E && typ[e] < 6) atomicAdd(&cnt[dst[e]], 1);
}

__global__ void k_add_i(const int* __restrict__ a, const int* __restrict__ b,
                        int* __restrict__ o, int n) {
  int i = blockIdx.x * 256 + threadIdx.x;
  if (i < n) o[i] = a[i] + b[i];
}

__global__ void k_scan_blk(const int* __restrict__ in, int* __restrict__ out,
                           int* __restrict__ part, int n) {
  __shared__ int s[256];
  int t = threadIdx.x;
  int g = blockIdx.x * 256 + t;
  int v = (g < n) ? in[g] : 0;
  s[t] = v;
  __syncthreads();
  for (int off = 1; off < 256; off <<= 1) {
    int add = (t >= off) ? s[t - off] : 0;
    __syncthreads();
    s[t] += add;
    __syncthreads();
  }
  if (g < n) out[g] = s[t] - v;
  if (t == 255) part[blockIdx.x] = s[255];
}

__global__ void k_scan_top(int* __restrict__ part, int nb) {
  __shared__ int s[256];
  int t = threadIdx.x;
  int v = (t < nb) ? part[t] : 0;
  s[t] = v;
  __syncthreads();
  for (int off = 1; off < 256; off <<= 1) {
    int add = (t >= off) ? s[t - off] : 0;
    __syncthreads();
    s[t] += add;
    __syncthreads();
  }
  if (t < nb) part[t] = s[t] - v;
}

__global__ void k_scan_add(int* __restrict__ out, const int* __restrict__ part, int n) {
  int g = blockIdx.x * 256 + threadIdx.x;
  if (g < n) out[g] += part[blockIdx.x];
}

__global__ void k_fill(const int* __restrict__ src, const int* __restrict__ dst,
                       int* __restrict__ cur, int* __restrict__ slots, int E) {
  int e = blockIdx.x * 256 + threadIdx.x;
  if (e >= E) return;
  int d = dst[e];
  int pos = atomicAdd(&cur[d], 1);
  slots[pos] = src[e];
}

// split fill: typ<6 edges go to [rp, bnd), others to [bnd, rp_next)
__global__ void k_fill_split(const int* __restrict__ src, const int* __restrict__ dst,
                             const int* __restrict__ typ, int* __restrict__ cur_a,
                             int* __restrict__ cur_b, int* __restrict__ slots, int E) {
  int e = blockIdx.x * 256 + threadIdx.x;
  if (e >= E) return;
  int d = dst[e];
  int* c = (typ[e] < 6) ? cur_a : cur_b;
  int pos = atomicAdd(&c[d], 1);
  slots[pos] = src[e] | (typ[e] << 16);
}

__global__ void k_dis_rp(const int* __restrict__ rp, float* __restrict__ dis, int n, int E) {
  int v = blockIdx.x * 256 + threadIdx.x;
  if (v >= n) return;
  int e0 = rp[v], e1 = (v + 1 < n) ? rp[v + 1] : E;
  dis[v] = rsqrtf((float)(e1 - e0) + 1.0f);
}

__global__ void k_count_type(const int* __restrict__ dst, const int* __restrict__ typ,
                             float* __restrict__ cnt, int E) {
  int i = blockIdx.x * 256 + threadIdx.x;
  if (i < E) atomicAdd(&cnt[(size_t)typ[i] * NE + dst[i]], 1.0f);
}

__global__ void k_rcp(float* __restrict__ c, size_t n) {
  size_t i = (size_t)blockIdx.x * 256 + threadIdx.x;
  if (i < n) { float v = c[i]; c[i] = (v > 0.f) ? 1.0f / v : 0.f; }
}

// ---------------------------------------------------------------------------
// bf16 gather kernel: one wave per dst row; a = dv*(dv*x[v] + sum dis[s]*x[s]).
// 2-edge unrolled (doubled memory-level parallelism on the latency-bound loop).
// OUTM: 0 none, 1 outb = bf16(a), 2 outb = bf16(acc_new).
// ACCM: 1 acc += sc*a; 2 acc = sc*(x[v]+a); 3 acc = sc*a.
// ---------------------------------------------------------------------------
template <int OUTM, int ACCM>
__global__ void k_gcn_gb(const unsigned short* __restrict__ x,
                         const float* __restrict__ dis,
                         const int* __restrict__ rp, const int* __restrict__ slots,
                         unsigned short* __restrict__ outb, float* __restrict__ acc,
                         int n, int E, float sc) {
  int v = (int)((blockIdx.x * (size_t)blockDim.x + threadIdx.x) >> 6);
  int lane = threadIdx.x & 63;
  if (v >= n) return;
  float dv = dis[v];
  const uint32_t* xr = (const uint32_t*)(x + (size_t)v * Dm);
  float xv[6];
#pragma unroll
  for (int i = 0; i < 3; ++i) {
    uint32_t u = xr[lane + 64 * i];
    xv[2 * i] = bflo(u); xv[2 * i + 1] = bfhi(u);
  }
  float a[6];
#pragma unroll
  for (int i = 0; i < 6; ++i) a[i] = dv * xv[i];
  int e0 = rp[v], e1 = (v + 1 < n) ? rp[v + 1] : E;
  int e = e0;
  for (; e + 2 <= e1; e += 2) {
    int s0 = slots[e], s1 = slots[e + 1];
    float c0 = dis[s0], c1 = dis[s1];
    const uint32_t* x0 = (const uint32_t*)(x + (size_t)s0 * Dm);
    const uint32_t* x1 = (const uint32_t*)(x + (size_t)s1 * Dm);
    uint32_t u0[3], u1[3];
#pragma unroll
    for (int i = 0; i < 3; ++i) { u0[i] = x0[lane + 64 * i]; u1[i] = x1[lane + 64 * i]; }
#pragma unroll
    for (int i = 0; i < 3; ++i) {
      a[2 * i]     = fmaf(c0, bflo(u0[i]), a[2 * i]);
      a[2 * i + 1] = fmaf(c0, bfhi(u0[i]), a[2 * i + 1]);
      a[2 * i]     = fmaf(c1, bflo(u1[i]), a[2 * i]);
      a[2 * i + 1] = fmaf(c1, bfhi(u1[i]), a[2 * i + 1]);
    }
  }
  if (e < e1) {
    int s0 = slots[e];
    float c0 = dis[s0];
    const uint32_t* x0 = (const uint32_t*)(x + (size_t)s0 * Dm);
#pragma unroll
    for (int i = 0; i < 3; ++i) {
      uint32_t u = x0[lane + 64 * i];
      a[2 * i]     = fmaf(c0, bflo(u), a[2 * i]);
      a[2 * i + 1] = fmaf(c0, bfhi(u), a[2 * i + 1]);
    }
  }
#pragma unroll
  for (int i = 0; i < 6; ++i) a[i] *= dv;
  if (OUTM == 1) {
    uint32_t* ob = (uint32_t*)(outb + (size_t)v * Dm);
#pragma unroll
    for (int i = 0; i < 3; ++i) ob[lane + 64 * i] = pkbf(a[2 * i], a[2 * i + 1]);
  }
  float* ar = acc + (size_t)v * Dm;
  float nw[6];
#pragma unroll
  for (int i = 0; i < 3; ++i) {
    int cidx = 2 * (lane + 64 * i);
    if (ACCM == 1) {
      float2 old = *(const float2*)(ar + cidx);
      nw[2 * i] = old.x + sc * a[2 * i];
      nw[2 * i + 1] = old.y + sc * a[2 * i + 1];
    } else if (ACCM == 2) {
      nw[2 * i] = sc * (xv[2 * i] + a[2 * i]);
      nw[2 * i + 1] = sc * (xv[2 * i + 1] + a[2 * i + 1]);
    } else {
      nw[2 * i] = sc * a[2 * i];
      nw[2 * i + 1] = sc * a[2 * i + 1];
    }
    *(float2*)(ar + cidx) = float2{nw[2 * i], nw[2 * i + 1]};
  }
  if (OUTM == 2) {
    uint32_t* ob = (uint32_t*)(outb + (size_t)v * Dm);
#pragma unroll
    for (int i = 0; i < 3; ++i) ob[lane + 64 * i] = pkbf(nw[2 * i], nw[2 * i + 1]);
  }
}

// ---------------------------------------------------------------------------
// RGCN gather, split-range (FIRST: r<6 edges in [rp,bnd); else [bnd,rp_next)),
// 2-edge unrolled, filter-free. EMITB: also emit ent0b bf16 (last call).
// ---------------------------------------------------------------------------
template <bool FIRST, bool EMITB>
__global__ void k_rgcn_g(const unsigned short* __restrict__ hh, const float* __restrict__ rcp,
                         const int* __restrict__ rp, const int* __restrict__ bnd,
                         const int* __restrict__ slots, float* __restrict__ ent0,
                         unsigned short* __restrict__ outb, int E) {
  int v = (int)((blockIdx.x * (size_t)blockDim.x + threadIdx.x) >> 6);
  int lane = threadIdx.x & 63;
  if (v >= NE) return;
  const int rbase = FIRST ? 0 : 6;
  int e0, e1;
  if (FIRST) { e0 = rp[v]; e1 = bnd[v]; }
  else       { e0 = bnd[v]; e1 = (v + 1 < NE) ? rp[v + 1] : E; }
  float* er = ent0 + (size_t)v * Dm;
  float2 a[3];
#pragma unroll
  for (int i = 0; i < 3; ++i) a[i] = *(const float2*)(er + 2 * lane + 128 * i);
  int e = e0;
  for (; e + 2 <= e1; e += 2) {
    int p0 = slots[e], p1 = slots[e + 1];
    int r0 = (p0 >> 16) - rbase, s0 = p0 & 0xFFFF;
    int r1 = (p1 >> 16) - rbase, s1 = p1 & 0xFFFF;
    float nm0 = rcp[(size_t)(r0 + rbase) * NE + v];
    float nm1 = rcp[(size_t)(r1 + rbase) * NE + v];
    const uint32_t* h0 = (const uint32_t*)(hh + (size_t)s0 * 2304 + (size_t)r0 * 384);
    const uint32_t* h1 = (const uint32_t*)(hh + (size_t)s1 * 2304 + (size_t)r1 * 384);
    uint32_t u0[3], u1[3];
#pragma unroll
    for (int i = 0; i < 3; ++i) { u0[i] = h0[lane + 64 * i]; u1[i] = h1[lane + 64 * i]; }
#pragma unroll
    for (int i = 0; i < 3; ++i) {
      a[i].x = fmaf(nm0, bflo(u0[i]), a[i].x);
      a[i].y = fmaf(nm0, bfhi(u0[i]), a[i].y);
      a[i].x = fmaf(nm1, bflo(u1[i]), a[i].x);
      a[i].y = fmaf(nm1, bfhi(u1[i]), a[i].y);
    }
  }
  if (e < e1) {
    int p0 = slots[e];
    int r0 = (p0 >> 16) - rbase, s0 = p0 & 0xFFFF;
    float nm0 = rcp[(size_t)(r0 + rbase) * NE + v];
    const uint32_t* h0 = (const uint32_t*)(hh + (size_t)s0 * 2304 + (size_t)r0 * 384);
#pragma unroll
    for (int i = 0; i < 3; ++i) {
      uint32_t u = h0[lane + 64 * i];
      a[i].x = fmaf(nm0, bflo(u), a[i].x);
      a[i].y = fmaf(nm0, bfhi(u), a[i].y);
    }
  }
#pragma unroll
  for (int i = 0; i < 3; ++i) *(float2*)(er + 2 * lane + 128 * i) = a[i];
  if (EMITB) {
    uint32_t* ob = (uint32_t*)(outb + (size_t)v * Dm);
#pragma unroll
    for (int i = 0; i < 3; ++i) ob[lane + 64 * i] = pkbf(a[i].x, a[i].y);
  }
}

// ---------------------------------------------------------------------------
// bf16 MFMA GEMM, 128x128 (m97 structure). A[M][K], Wt[N][K] bf16.
// OUT: 0 = f32 C, 1 = bf16 C, 2 = f32 transposed prompt layout.
// ---------------------------------------------------------------------------
template <bool RELU, bool RES, int OUT>
__global__ __launch_bounds__(256) void mgemm_bf(
    const unsigned short* __restrict__ A, const unsigned short* __restrict__ Wt,
    const float* __restrict__ bias, const float* __restrict__ Rp,
    void* __restrict__ Cv, int M, int N, int K) {
  __shared__ __align__(16) unsigned short As[128 * 64];
  __shared__ __align__(16) unsigned short Bs[128 * 64];
  const int tid = threadIdx.x;
  const int lane = tid & 63;
  const int w = tid >> 6;
  const int bm = blockIdx.x * 128, bn = blockIdx.y * 128;
  const int wr = (w >> 1) * 64, wc = (w & 1) * 64;
  const int lrow = lane & 15, lq = lane >> 4;
  f32x4 acc[4][4] = {};
  const int prow_l = lane >> 3;
  const int pslot = lane & 7;

  for (int k0 = 0; k0 < K; k0 += 64) {
    __syncthreads();
#pragma unroll
    for (int j = 0; j < 4; ++j) {
      int seg = j * 4 + w;
      int prow = seg * 8 + prow_l;
      int aslot = pslot ^ (prow & 7);
      int arow = min(bm + prow, M - 1);
      gl16(A + (size_t)arow * K + k0 + aslot * 8, &As[seg * 512 + lane * 8]);
    }
#pragma unroll
    for (int j = 0; j < 4; ++j) {
      int seg = j * 4 + w;
      int prow = seg * 8 + prow_l;
      int bslot = pslot ^ (prow & 7);
      int brow = min(bn + prow, N - 1);
      gl16(Wt + (size_t)brow * K + k0 + bslot * 8, &Bs[seg * 512 + lane * 8]);
    }
    __syncthreads();
#pragma unroll
    for (int ks = 0; ks < 2; ++ks) {
      short8v af[4], bf[4];
      const int slot = ks * 4 + lq;
#pragma unroll
      for (int mr = 0; mr < 4; ++mr) {
        int r = wr + mr * 16 + lrow;
        af[mr] = *(const short8v*)&As[r * 64 + ((slot ^ (r & 7)) << 3)];
      }
#pragma unroll
      for (int nc = 0; nc < 4; ++nc) {
        int r = wc + nc * 16 + lrow;
        bf[nc] = *(const short8v*)&Bs[r * 64 + ((slot ^ (r & 7)) << 3)];
      }
#pragma unroll
      for (int mr = 0; mr < 4; ++mr)
#pragma unroll
        for (int nc = 0; nc < 4; ++nc)
          acc[mr][nc] = __builtin_amdgcn_mfma_f32_16x16x32_bf16(
              af[mr], bf[nc], acc[mr][nc], 0, 0, 0);
    }
  }
#pragma unroll
  for (int mr = 0; mr < 4; ++mr) {
#pragma unroll
    for (int e = 0; e < 4; ++e) {
      int r = bm + wr + mr * 16 + lq * 4 + e;
      if (r >= M) continue;
#pragma unroll
      for (int nc = 0; nc < 4; ++nc) {
        int c = bn + wc + nc * 16 + lrow;
        if (c >= N) continue;
        float v = acc[mr][nc][e];
        if (bias) v += bias[c];
        if (RES) v += Rp[(size_t)r * N + c];
        if (RELU) v = fmaxf(v, 0.f);
        if (OUT == 0) {
          ((float*)Cv)[(size_t)r * N + c] = v;
        } else if (OUT == 1) {
          ((unsigned short*)Cv)[(size_t)r * N + c] = f2bf(v);
        } else {
          int b = r >> 8, t = r & 255;
          int l = c / 1536, rem = c - l * 1536;
          int blk = rem / 768, rem2 = rem - blk * 768;
          int hh = rem2 >> 6, dd = rem2 & 63;
          size_t oi = (((((size_t)l * 2 + blk) * 16 + b) * 12 + hh) * 256 + t) * 64 + dd;
          ((float*)Cv)[oi] = v;
        }
      }
    }
  }
}

// Fallback FINAL GEMM (ws too small): W f32 from d_in, in-kernel conversion.
__global__ __launch_bounds__(256) void mgemm_fin(
    const unsigned short* __restrict__ A, const float* __restrict__ W,
    const float* __restrict__ bias, float* __restrict__ O, int M, int N, int K) {
  __shared__ __align__(16) unsigned short As[128 * 64];
  __shared__ __align__(16) unsigned short Bs[128 * 64];
  const int tid = threadIdx.x;
  const int lane = tid & 63;
  const int w = tid >> 6;
  const int bm = blockIdx.x * 128, bn = blockIdx.y * 128;
  const int wr = (w >> 1) * 64, wc = (w & 1) * 64;
  const int lrow = lane & 15, lq = lane >> 4;
  f32x4 acc[4][4] = {};
  const int prow_l = lane >> 3;
  const int pslot = lane & 7;
  const int n_loc = tid & 127;
  const int kh = (tid >> 7) * 32;

  for (int k0 = 0; k0 < K; k0 += 64) {
    __syncthreads();
#pragma unroll
    for (int j = 0; j < 4; ++j) {
      int seg = j * 4 + w;
      int prow = seg * 8 + prow_l;
      int aslot = pslot ^ (prow & 7);
      gl16(A + (size_t)(bm + prow) * K + k0 + aslot * 8, &As[seg * 512 + lane * 8]);
    }
    float wv[32];
    const float* wp = W + (size_t)(k0 + kh) * N + bn + n_loc;
#pragma unroll
    for (int j = 0; j < 32; ++j) wv[j] = wp[(size_t)j * N];
#pragma unroll
    for (int c = 0; c < 4; ++c) {
      uint32_t u0 = pkbf(wv[8 * c + 0], wv[8 * c + 1]);
      uint32_t u1 = pkbf(wv[8 * c + 2], wv[8 * c + 3]);
      uint32_t u2 = pkbf(wv[8 * c + 4], wv[8 * c + 5]);
      uint32_t u3 = pkbf(wv[8 * c + 6], wv[8 * c + 7]);
      int s = (kh >> 3) + c;
      *(uint4*)&Bs[n_loc * 64 + ((s ^ (n_loc & 7)) << 3)] = uint4{u0, u1, u2, u3};
    }
    __syncthreads();
#pragma unroll
    for (int ks = 0; ks < 2; ++ks) {
      short8v af[4], bf[4];
      const int slot = ks * 4 + lq;
#pragma unroll
      for (int mr = 0; mr < 4; ++mr) {
        int r = wr + mr * 16 + lrow;
        af[mr] = *(const short8v*)&As[r * 64 + ((slot ^ (r & 7)) << 3)];
      }
#pragma unroll
      for (int nc = 0; nc < 4; ++nc) {
        int r = wc + nc * 16 + lrow;
        bf[nc] = *(const short8v*)&Bs[r * 64 + ((slot ^ (r & 7)) << 3)];
      }
#pragma unroll
      for (int mr = 0; mr < 4; ++mr)
#pragma unroll
        for (int nc = 0; nc < 4; ++nc)
          acc[mr][nc] = __builtin_amdgcn_mfma_f32_16x16x32_bf16(
              af[mr], bf[nc], acc[mr][nc], 0, 0, 0);
    }
  }
#pragma unroll
  for (int mr = 0; mr < 4; ++mr) {
#pragma unroll
    for (int e = 0; e < 4; ++e) {
      int r = bm + wr + mr * 16 + lq * 4 + e;
      int b = r >> 8, t = r & 255;
#pragma unroll
      for (int nc = 0; nc < 4; ++nc) {
        int c = bn + wc + nc * 16 + lrow;
        float v = acc[mr][nc][e] + bias[c];
        int l = c / 1536, rem = c - l * 1536;
        int blk = rem / 768, rem2 = rem - blk * 768;
        int hh = rem2 >> 6, dd = rem2 & 63;
        size_t oi = (((((size_t)l * 2 + blk) * 16 + b) * 12 + hh) * 256 + t) * 64 + dd;
        O[oi] = v;
      }
    }
  }
}

// ---------------------------------------------------------------------------
// fused cross-attention (bf16 inputs): one wave per (b,t)
// ---------------------------------------------------------------------------
__global__ __launch_bounds__(256) void k_attn(
    const unsigned short* __restrict__ qb, const unsigned short* __restrict__ eb_all,
    const unsigned short* __restrict__ tokb, float* __restrict__ pr0,
    unsigned short* __restrict__ pr0b) {
  int gw = (int)((blockIdx.x * (size_t)blockDim.x + threadIdx.x) >> 6);
  int lane = threadIdx.x & 63;
  if (gw >= NTOK) return;
  int b = gw >> 8;
  const unsigned short* qr = qb + (size_t)gw * Hm;
  float2 q[6];
#pragma unroll
  for (int i = 0; i < 6; ++i) {
    uint32_t u = *(const uint32_t*)(qr + 2 * lane + 128 * i);
    q[i] = float2{bflo(u), bfhi(u)};
  }
  const unsigned short* eb = eb_all + (size_t)b * LE * Hm;
  float myA = -3.0e38f;
  for (int e = 0; e < LE; ++e) {
    const unsigned short* er = eb + (size_t)e * Hm;
    float s = 0.f;
#pragma unroll
    for (int i = 0; i < 6; ++i) {
      uint32_t u = *(const uint32_t*)(er + 2 * lane + 128 * i);
      s = fmaf(q[i].x, bflo(u), s);
      s = fmaf(q[i].y, bfhi(u), s);
    }
#pragma unroll
    for (int off = 32; off > 0; off >>= 1) s += __shfl_xor(s, off);
    if (lane == e) myA = s * (1.0f / 768.0f);
  }
  float mx = myA;
#pragma unroll
  for (int off = 32; off > 0; off >>= 1) mx = fmaxf(mx, __shfl_xor(mx, off));
  float p = (lane < LE) ? expf(myA - mx) : 0.f;
  float sum = p;
#pragma unroll
  for (int off = 32; off > 0; off >>= 1) sum += __shfl_xor(sum, off);
  float wgt = p / sum;
  const unsigned short* tr = tokb + (size_t)gw * Hm;
  float2 a[6];
#pragma unroll
  for (int i = 0; i < 6; ++i) {
    uint32_t u = *(const uint32_t*)(tr + 2 * lane + 128 * i);
    a[i] = float2{bflo(u), bfhi(u)};
  }
  for (int e = 0; e < LE; ++e) {
    float we = __shfl(wgt, e);
    const unsigned short* er = eb + (size_t)e * Hm;
#pragma unroll
    for (int i = 0; i < 6; ++i) {
      uint32_t u = *(const uint32_t*)(er + 2 * lane + 128 * i);
      a[i].x = fmaf(we, bflo(u), a[i].x);
      a[i].y = fmaf(we, bfhi(u), a[i].y);
    }
  }
  float* orow = pr0 + (size_t)gw * Hm;
  unsigned short* obrow = pr0b + (size_t)gw * Hm;
#pragma unroll
  for (int i = 0; i < 6; ++i) {
    *(float2*)(orow + 2 * lane + 128 * i) = a[i];
    *(uint32_t*)(obrow + 2 * lane + 128 * i) = pkbf(a[i].x, a[i].y);
  }
}

// ---------------------------------------------------------------------------

extern "C" void kernel_launch(void* const* d_in, const int* in_sizes, int n_in,
                              void* d_out, int out_size, void* d_ws, size_t ws_size,
                              hipStream_t stream) {
  (void)in_sizes; (void)n_in; (void)out_size;

  const float* x_node = (const float*)d_in[0];
  const float* bases  = (const float*)d_in[1];
  const float* comp   = (const float*)d_in[2];
  const float* root   = (const float*)d_in[3];
  const float* rbias  = (const float*)d_in[4];
  const float* ep1w1  = (const float*)d_in[5];
  const float* ep1b1  = (const float*)d_in[6];
  const float* ep1w2  = (const float*)d_in[7];
  const float* ep1b2  = (const float*)d_in[8];
  const float* ep2w   = (const float*)d_in[9];
  const float* ep2b   = (const float*)d_in[10];
  const float* tp1w1  = (const float*)d_in[11];
  const float* tp1b1  = (const float*)d_in[12];
  const float* tp1w2  = (const float*)d_in[13];
  const float* tp1b2  = (const float*)d_in[14];
  const float* tp2w   = (const float*)d_in[15];
  const float* tp2b   = (const float*)d_in[16];
  const float* caw    = (const float*)d_in[17];
  const float* pp1w1  = (const float*)d_in[18];
  const float* pp1b1  = (const float*)d_in[19];
  const float* pp1w2  = (const float*)d_in[20];
  const float* pp1b2  = (const float*)d_in[21];
  const float* pp2w   = (const float*)d_in[22];
  const float* pp2b   = (const float*)d_in[23];
  const float* tokens = (const float*)d_in[24];
  const int* ei_kg = (const int*)d_in[25];
  const int* etype = (const int*)d_in[26];
  const int* ei_c  = (const int*)d_in[27];
  const int* ei_ts = (const int*)d_in[28];
  const int* ei_is = (const int*)d_in[29];
  const int* mte   = (const int*)d_in[30];
  const int* eids  = (const int*)d_in[31];

  float* O = (float*)d_out;
  unsigned short* xb    = (unsigned short*)(O + P_XB);
  unsigned short* wct   = (unsigned short*)(O + P_WCT);
  float* rcpc  = O + P_CNT;
  float* ent0  = O + P_ENT0;
  unsigned short* hh    = (unsigned short*)(O + P_HH);
  float* disc  = O + P_DIS;
  float* dist  = O + P_DIS + 30000;
  float* disi  = O + P_DIS + 36000;
  unsigned short* ent0b = (unsigned short*)(O + P_E0B);
  unsigned short* c1b   = (unsigned short*)(O + P_C1B);
  unsigned short* c2b   = (unsigned short*)(O + P_C2B);
  unsigned short* nfb   = (unsigned short*)(O + P_NFB);
  unsigned short* t1b   = (unsigned short*)(O + P_T1B);
  float* g1    = O + P_G1;
  float* accb  = O + P_ACC;
  unsigned short* entb  = (unsigned short*)(O + P_ENTB);
  unsigned short* hidb  = (unsigned short*)(O + P_HIDB);
  unsigned short* ent2b = (unsigned short*)(O + P_ENT2B);
  unsigned short* e768b = (unsigned short*)(O + P_E768B);
  unsigned short* tokb  = (unsigned short*)(O + P_TOKB);
  unsigned short* thidb = (unsigned short*)(O + P_THIDB);
  unsigned short* tok1b = (unsigned short*)(O + P_TOK1B);
  unsigned short* tok2b = (unsigned short*)(O + P_TOK2B);
  unsigned short* qb    = (unsigned short*)(O + P_QB);
  unsigned short* eemb  = (unsigned short*)(O + P_EEMB);
  float* pr0   = O + P_PR0;
  unsigned short* pr0b  = (unsigned short*)(O + P_PR0B);
  unsigned short* phidb = (unsigned short*)(O + P_PHIDB);
  unsigned short* wts   = (unsigned short*)(O + P_WT);

  int* iws = (int*)d_ws;
  unsigned short* p2b = (unsigned short*)d_ws;
  unsigned short* pp2t = (unsigned short*)d_ws + WS_PP2T_BYTE / 2;
  const bool ws_ok = (ws_size >= WS_NEED);
  int* cnt_i  = iws + I_CNT;
  int* part   = iws + I_PART;
  int* kg_rp  = iws + I_KG_RP;  int* kg_ca = iws + I_KG_CA;  int* kg_sl = iws + I_KG_SL;
  int* kg_bnd = iws + I_KG_BND; int* kg_cb = iws + I_KG_CB;
  int* c_rp   = iws + I_C_RP;   int* c_cur  = iws + I_C_CUR;   int* c_sl  = iws + I_C_SL;
  int* ts_rp  = iws + I_TS_RP;  int* ts_cur = iws + I_TS_CUR;  int* ts_sl = iws + I_TS_SL;
  int* is_rp  = iws + I_IS_RP;  int* is_cur = iws + I_IS_CUR;  int* is_sl = iws + I_IS_SL;

  const int EW = 256;

  // ---------------- phase A: conversions ----------------
  k_cvt<<<cdiv(NBf / 2, EW), EW, 0, stream>>>(x_node, xb, NBf / 2);
  k_wcat<<<cdiv(12 * Dm * Dm, EW), EW, 0, stream>>>(comp, bases, wct);
  k_cvt_t<<<dim3(Dm / 32, Dm / 32), 256, 0, stream>>>(root, wts + S_ROOT, Dm, Dm);
  k_cvt_t<<<dim3(192 / 32, Dm / 32), 256, 0, stream>>>(ep1w1, wts + S_EP1A, Dm, 192);
  k_cvt_t<<<dim3(Dm / 32, 192 / 32), 256, 0, stream>>>(ep1w2, wts + S_EP1B, 192, Dm);
  k_cvt_t<<<dim3(Hm / 32, Dm / 32), 256, 0, stream>>>(ep2w, wts + S_EP2, Dm, Hm);
  k_cvt_t<<<dim3(Dm / 32, Hm / 32), 256, 0, stream>>>(tp1w1, wts + S_TP1A, Hm, Dm);
  k_cvt_t<<<dim3(Hm / 32, Dm / 32), 256, 0, stream>>>(tp1w2, wts + S_TP1B, Dm, Hm);
  k_cvt_t<<<dim3(Hm / 32, Hm / 32), 256, 0, stream>>>(tp2w, wts + S_TP2, Hm, Hm);
  k_cvt_t<<<dim3(Hm / 32, Hm / 32), 256, 0, stream>>>(caw, wts + S_CAW, Hm, Hm);
  k_cvt_t<<<dim3(Dm / 32, Hm / 32), 256, 0, stream>>>(pp1w1, wts + S_PP1A, Hm, Dm);
  k_cvt_t<<<dim3(Hm / 32, Dm / 32), 256, 0, stream>>>(pp1w2, wts + S_PP1B, Dm, Hm);

  // ---------------- CSR builds ----------------
  // KG graph: split CSR (typ<6 in [rp,bnd), typ>=6 in [bnd,rp_next))
  hipMemsetAsync(cnt_i, 0, (size_t)NE * 4, stream);
  k_hist<<<cdiv(EKG, EW), EW, 0, stream>>>(ei_kg + EKG, cnt_i, EKG);
  {
    int nb = cdiv(NE, 256);
    k_scan_blk<<<nb, 256, 0, stream>>>(cnt_i, kg_rp, part, NE);
    k_scan_top<<<1, 256, 0, stream>>>(part, nb);
    k_scan_add<<<nb, 256, 0, stream>>>(kg_rp, part, NE);
  }
  hipMemsetAsync(cnt_i, 0, (size_t)NE * 4, stream);
  k_hist_lt<<<cdiv(EKG, EW), EW, 0, stream>>>(ei_kg + EKG, etype, cnt_i, EKG);
  k_add_i<<<cdiv(NE, EW), EW, 0, stream>>>(kg_rp, cnt_i, kg_bnd, NE);
  hipMemcpyAsync(kg_ca, kg_rp, (size_t)NE * 4, hipMemcpyDeviceToDevice, stream);
  hipMemcpyAsync(kg_cb, kg_bnd, (size_t)NE * 4, hipMemcpyDeviceToDevice, stream);
  k_fill_split<<<cdiv(EKG, EW), EW, 0, stream>>>(
      ei_kg, ei_kg + EKG, etype, kg_ca, kg_cb, kg_sl, EKG);

  auto build_csr = [&](const int* ei, int n, int E, int* rp, int* cur, int* sl) {
    hipMemsetAsync(cnt_i, 0, (size_t)n * 4, stream);
    k_hist<<<cdiv(E, EW), EW, 0, stream>>>(ei + E, cnt_i, E);
    int nb = cdiv(n, 256);
    k_scan_blk<<<nb, 256, 0, stream>>>(cnt_i, rp, part, n);
    k_scan_top<<<1, 256, 0, stream>>>(part, nb);
    k_scan_add<<<nb, 256, 0, stream>>>(rp, part, n);
    hipMemcpyAsync(cur, rp, (size_t)n * 4, hipMemcpyDeviceToDevice, stream);
    k_fill<<<cdiv(E, EW), EW, 0, stream>>>(ei, ei + E, cur, sl, E);
  };
  build_csr(ei_c, NE, EC, c_rp, c_cur, c_sl);
  build_csr(ei_ts, NM, ES, ts_rp, ts_cur, ts_sl);
  build_csr(ei_is, NM, ES, is_rp, is_cur, is_sl);

  k_dis_rp<<<cdiv(NE, EW), EW, 0, stream>>>(c_rp, disc, NE, EC);
  k_dis_rp<<<cdiv(NM, EW), EW, 0, stream>>>(ts_rp, dist, NM, ES);
  k_dis_rp<<<cdiv(NM, EW), EW, 0, stream>>>(is_rp, disi, NM, ES);

  hipMemsetAsync(rcpc, 0, (size_t)12 * NE * 4, stream);
  k_count_type<<<cdiv(EKG, EW), EW, 0, stream>>>(ei_kg + EKG, etype, rcpc, EKG);
  k_rcp<<<cdiv((long)12 * NE, EW), EW, 0, stream>>>(rcpc, (size_t)12 * NE);

  // ---------------- RGCN ----------------
  mgemm_bf<false, true, 0><<<dim3(cdiv(NE, 128), cdiv(Dm, 128)), 256, 0, stream>>>(
      xb, wts + S_ROOT, rbias, x_node, ent0, NE, Dm, Dm);
  mgemm_bf<false, false, 1><<<dim3(cdiv(NE, 128), cdiv(6 * Dm, 128)), 256, 0, stream>>>(
      xb, wct, nullptr, nullptr, hh, NE, 6 * Dm, Dm);
  k_rgcn_g<true, false><<<cdiv((long)NE * 64, EW), EW, 0, stream>>>(
      hh, rcpc, kg_rp, kg_bnd, kg_sl, ent0, nullptr, EKG);
  mgemm_bf<false, false, 1><<<dim3(cdiv(NE, 128), cdiv(6 * Dm, 128)), 256, 0, stream>>>(
      xb, wct + (size_t)6 * Dm * Dm, nullptr, nullptr, hh, NE, 6 * Dm, Dm);
  // last RGCN gather also emits ent0b (bf16) — xb dead by now
  k_rgcn_g<false, true><<<cdiv((long)NE * 64, EW), EW, 0, stream>>>(
      hh, rcpc, kg_rp, kg_bnd, kg_sl, ent0, ent0b, EKG);

  // ---------------- phase B: graph chains (bf16) ----------------
  k_gather_b<<<cdiv((long)NM * 192, EW), EW, 0, stream>>>(
      mte, (const uint32_t*)ent0b, (uint32_t*)nfb, NM, 192);
  k_gcn_gb<1, 3><<<cdiv((long)NM * 64, EW), EW, 0, stream>>>(
      nfb, dist, ts_rp, ts_sl, t1b, g1, NM, ES, 1.0f);
  k_gcn_gb<0, 1><<<cdiv((long)NM * 64, EW), EW, 0, stream>>>(
      t1b, dist, ts_rp, ts_sl, nullptr, g1, NM, ES, 1.0f);
  k_gcn_gb<1, 1><<<cdiv((long)NM * 64, EW), EW, 0, stream>>>(
      nfb, disi, is_rp, is_sl, t1b, g1, NM, ES, 1.0f);
  k_gcn_gb<0, 1><<<cdiv((long)NM * 64, EW), EW, 0, stream>>>(
      t1b, disi, is_rp, is_sl, nullptr, g1, NM, ES, 1.0f);
  // entity chain (0.25 folded): accb = 0.25*(ent0+c1) += 0.25*c2 += movie += 0.25*c3
  k_gcn_gb<1, 2><<<cdiv((long)NE * 64, EW), EW, 0, stream>>>(
      ent0b, disc, c_rp, c_sl, c1b, accb, NE, EC, 0.25f);
  k_gcn_gb<1, 1><<<cdiv((long)NE * 64, EW), EW, 0, stream>>>(
      c1b, disc, c_rp, c_sl, c2b, accb, NE, EC, 0.25f);
  k_scatter_movie<<<cdiv(MBF, EW), EW, 0, stream>>>(mte, g1, accb);
  k_gcn_gb<2, 1><<<cdiv((long)NE * 64, EW), EW, 0, stream>>>(
      c2b, disc, c_rp, c_sl, entb, accb, NE, EC, 0.25f);

  // pp2t conversion (CSR arrays now dead)
  if (ws_ok) {
    k_cvt_t<<<dim3(NO / 32, Hm / 32), 256, 0, stream>>>(pp2w, pp2t, Hm, NO);
  }

  // ---------------- entity MLP ----------------
  mgemm_bf<true, false, 1><<<dim3(cdiv(NE, 128), cdiv(192, 128)), 256, 0, stream>>>(
      entb, wts + S_EP1A, ep1b1, nullptr, hidb, NE, 192, Dm);
  mgemm_bf<false, true, 1><<<dim3(cdiv(NE, 128), cdiv(Dm, 128)), 256, 0, stream>>>(
      hidb, wts + S_EP1B, ep1b2, accb, ent2b, NE, Dm, 192);
  mgemm_bf<false, false, 1><<<dim3(cdiv(NE, 128), cdiv(Hm, 128)), 256, 0, stream>>>(
      ent2b, wts + S_EP2, ep2b, nullptr, e768b, NE, Hm, Dm);

  // ---------------- token path ----------------
  k_cvt<<<cdiv((long)NTOK * Hm / 2, EW), EW, 0, stream>>>(tokens, tokb, (size_t)NTOK * Hm / 2);
  mgemm_bf<true, false, 1><<<dim3(cdiv(NTOK, 128), cdiv(Dm, 128)), 256, 0, stream>>>(
      tokb, wts + S_TP1A, tp1b1, nullptr, thidb, NTOK, Dm, Hm);
  mgemm_bf<false, true, 1><<<dim3(cdiv(NTOK, 128), cdiv(Hm, 128)), 256, 0, stream>>>(
      thidb, wts + S_TP1B, tp1b2, tokens, tok1b, NTOK, Hm, Dm);
  mgemm_bf<false, false, 1><<<dim3(cdiv(NTOK, 128), cdiv(Hm, 128)), 256, 0, stream>>>(
      tok1b, wts + S_TP2, tp2b, nullptr, tok2b, NTOK, Hm, Hm);
  mgemm_bf<false, false, 1><<<dim3(cdiv(NTOK, 128), cdiv(Hm, 128)), 256, 0, stream>>>(
      tok2b, wts + S_CAW, nullptr, nullptr, qb, NTOK, Hm, Hm);

  k_gather_b<<<cdiv((long)Bc * LE * (Hm / 2), EW), EW, 0, stream>>>(
      eids, (const uint32_t*)e768b, (uint32_t*)eemb, Bc * LE, Hm / 2);
  k_attn<<<cdiv((long)NTOK * 64, 256), 256, 0, stream>>>(qb, eemb, tok2b, pr0, pr0b);

  mgemm_bf<true, false, 1><<<dim3(cdiv(NTOK, 128), cdiv(Dm, 128)), 256, 0, stream>>>(
      pr0b, wts + S_PP1A, pp1b1, nullptr, phidb, NTOK, Dm, Hm);
  mgemm_bf<false, true, 1><<<dim3(cdiv(NTOK, 128), cdiv(Hm, 128)), 256, 0, stream>>>(
      phidb, wts + S_PP1B, pp1b2, pr0, p2b, NTOK, Hm, Dm);

  // ---------------- final GEMM + transpose (reads ONLY d_ws/d_in) ---------
  if (ws_ok) {
    mgemm_bf<false, false, 2><<<dim3(NTOK / 128, NO / 128), 256, 0, stream>>>(
        p2b, pp2t, pp2b, nullptr, O, NTOK, NO, Hm);
  } else {
    mgemm_fin<<<dim3(NTOK / 128, NO / 128), 256, 0, stream>>>(
        p2b, pp2w, pp2b, O, NTOK, NO, Hm);
  }
}